// Round 2
// baseline (7159.007 us; speedup 1.0000x reference)
//
#include <hip/hip_runtime.h>
#include <hip/hip_bf16.h>

#define D 128

// ---------------- f32 copy ----------------
__global__ void k_copy(const float* __restrict__ src, float* __restrict__ dst, int n4){
  int i = blockIdx.x*blockDim.x + threadIdx.x;
  for (; i < n4; i += gridDim.x*blockDim.x){
    ((float4*)dst)[i] = ((const float4*)src)[i];
  }
}

// ---------------- CSR build ----------------
__global__ void k_count(const int* __restrict__ ei1, const int* __restrict__ ei2,
                        int E1, int E2, int N1, int* __restrict__ cnt){
  int i = blockIdx.x*blockDim.x + threadIdx.x;
  int Et = E1 + E2;
  for (; i < Et; i += gridDim.x*blockDim.x){
    int dst = (i < E1) ? ei1[E1 + i] : (ei2[E2 + (i - E1)] + N1);
    atomicAdd(&cnt[dst], 1);
  }
}

__global__ void k_scan(const int* __restrict__ cnt, int* __restrict__ ptr,
                       int* __restrict__ cursor, float* __restrict__ degf, int N){
  __shared__ int part[256];
  int t = threadIdx.x;
  int per = (N + 255) >> 8;
  int lo = t*per, hi = min(N, lo+per);
  int s = 0;
  for (int j=lo;j<hi;j++) s += cnt[j];
  part[t] = s; __syncthreads();
  if (t==0){ int acc=0; for (int j=0;j<256;j++){ int v=part[j]; part[j]=acc; acc+=v; } }
  __syncthreads();
  int acc = part[t];
  for (int j=lo;j<hi;j++){ ptr[j]=acc; cursor[j]=acc; degf[j]=(float)cnt[j]; acc += cnt[j]; }
}

__global__ void k_fill(const int* __restrict__ ei1, const int* __restrict__ ei2,
                       int E1, int E2, int N1, int* __restrict__ cursor, int* __restrict__ srclist){
  int i = blockIdx.x*blockDim.x + threadIdx.x;
  int Et = E1 + E2;
  for (; i < Et; i += gridDim.x*blockDim.x){
    int src, dst;
    if (i < E1){ src = ei1[i]; dst = ei1[E1+i]; }
    else { int j = i - E1; src = ei2[j] + N1; dst = ei2[E2+j] + N1; }
    int p = atomicAdd(&cursor[dst], 1);
    srclist[p] = src;
  }
}

// S[v] = sum over in-edges of h[src]
__global__ __launch_bounds__(256) void k_gather(const float* __restrict__ h, const int* __restrict__ ptr,
                          const int* __restrict__ cnt, const int* __restrict__ srclist,
                          float* __restrict__ S, int N){
  int f = threadIdx.x & 127, sub = threadIdx.x >> 7;
  int v = blockIdx.x*2 + sub;
  if (v >= N) return;
  int b = ptr[v], n = cnt[v];
  float acc = 0.f;
  for (int j=0;j<n;j++){ acc += h[(size_t)srclist[b+j]*D + f]; }
  S[(size_t)v*D + f] = acc;
}

// ---------------- generic N x 128 GEMM:  Y = (sA.A)@W1 [+ B@W2] + bscale*bias ----------------
__global__ __launch_bounds__(256) void k_matmul(
    const float* __restrict__ A, const float* __restrict__ W1,
    const float* __restrict__ B, const float* __restrict__ W2,
    const float* __restrict__ bias,
    const float* __restrict__ rowScaleA, const float* __restrict__ biasScale,
    float* __restrict__ Y, int N)
{
  __shared__ float As[64][D];
  __shared__ float Bs[64][D];
  int t = threadIdx.x;
  int tx = t & 31, ty = t >> 5;
  int c0 = tx * 4;
  int rb = blockIdx.x * 64;
  if (rb >= N) return;
  for (int idx = t; idx < 64*32; idx += 256){
    int r = idx >> 5, cc = (idx & 31) * 4;
    float4 av = *(const float4*)&A[(size_t)(rb+r)*D + cc];
    if (rowScaleA){ float sc = rowScaleA[rb+r]; av.x*=sc; av.y*=sc; av.z*=sc; av.w*=sc; }
    *(float4*)&As[r][cc] = av;
    if (B) *(float4*)&Bs[r][cc] = *(const float4*)&B[(size_t)(rb+r)*D + cc];
  }
  __syncthreads();
  float acc[8][4];
  #pragma unroll
  for (int i=0;i<8;i++){ acc[i][0]=0.f;acc[i][1]=0.f;acc[i][2]=0.f;acc[i][3]=0.f; }
  for (int k=0;k<D;k++){
    float4 wv = *(const float4*)&W1[k*D + c0];
    #pragma unroll
    for (int i=0;i<8;i++){
      float a = As[ty*8+i][k];
      acc[i][0] += a*wv.x; acc[i][1] += a*wv.y; acc[i][2] += a*wv.z; acc[i][3] += a*wv.w;
    }
  }
  if (B){
    for (int k=0;k<D;k++){
      float4 wv = *(const float4*)&W2[k*D + c0];
      #pragma unroll
      for (int i=0;i<8;i++){
        float b = Bs[ty*8+i][k];
        acc[i][0] += b*wv.x; acc[i][1] += b*wv.y; acc[i][2] += b*wv.z; acc[i][3] += b*wv.w;
      }
    }
  }
  float b0=0.f,b1=0.f,b2=0.f,b3=0.f;
  if (bias){ float4 bv = *(const float4*)&bias[c0]; b0=bv.x; b1=bv.y; b2=bv.z; b3=bv.w; }
  #pragma unroll
  for (int i=0;i<8;i++){
    int r = rb + ty*8 + i;
    float bs = biasScale ? biasScale[r] : 1.0f;
    float4 o; o.x = acc[i][0] + b0*bs; o.y = acc[i][1] + b1*bs; o.z = acc[i][2] + b2*bs; o.w = acc[i][3] + b3*bs;
    *(float4*)&Y[(size_t)r*D + c0] = o;
  }
}

// ---------------- fused flash cross-attention, writes att_in = x - att ----------------
__global__ __launch_bounds__(256) void k_flash_attin(
    const float* __restrict__ x, int N1, int N2, float* __restrict__ attin)
{
  __shared__ float Qs[32][D];
  __shared__ float Ks[64][D+1];
  __shared__ float Ps[32][64];
  int t = threadIdx.x, tx = t & 31, ty = t >> 5;
  int nqb1 = N1 >> 5;
  bool isY = (int)blockIdx.x >= nqb1;
  int qbase = isY ? N1 + ((int)blockIdx.x - nqb1)*32 : (int)blockIdx.x*32;
  int kbase = isY ? 0 : N1;
  int nk = isY ? N1 : N2;
  for (int idx = t; idx < 32*32; idx += 256){
    int r = idx>>5, cc=(idx&31)*4;
    *(float4*)&Qs[r][cc] = *(const float4*)&x[(size_t)(qbase+r)*D + cc];
  }
  float m[4], l[4], O[4][4];
  #pragma unroll
  for (int i=0;i<4;i++){ m[i]=-3.0e38f; l[i]=0.f; O[i][0]=O[i][1]=O[i][2]=O[i][3]=0.f; }
  int c0 = tx*4;
  int k0 = 2*tx, k1 = 2*tx+1;
  for (int kb=0; kb<nk; kb+=64){
    __syncthreads();
    for (int idx=t; idx<64*D; idx+=256){
      int r = idx>>7, c = idx&127;
      Ks[r][c] = x[(size_t)(kbase+kb+r)*D + c];
    }
    __syncthreads();
    float s0[4]={0.f,0.f,0.f,0.f}, s1[4]={0.f,0.f,0.f,0.f};
    for (int d=0; d<D; d+=4){
      float ka0=Ks[k0][d], ka1=Ks[k0][d+1], ka2=Ks[k0][d+2], ka3=Ks[k0][d+3];
      float kb0=Ks[k1][d], kb1=Ks[k1][d+1], kb2=Ks[k1][d+2], kb3=Ks[k1][d+3];
      #pragma unroll
      for (int i=0;i<4;i++){
        float4 q = *(const float4*)&Qs[ty*4+i][d];
        s0[i] += q.x*ka0 + q.y*ka1 + q.z*ka2 + q.w*ka3;
        s1[i] += q.x*kb0 + q.y*kb1 + q.z*kb2 + q.w*kb3;
      }
    }
    #pragma unroll
    for (int i=0;i<4;i++){
      float tm = fmaxf(s0[i], s1[i]);
      #pragma unroll
      for (int off=16; off; off>>=1) tm = fmaxf(tm, __shfl_xor(tm, off, 32));
      float mnew = fmaxf(m[i], tm);
      float alpha = __expf(m[i]-mnew);
      float p0 = __expf(s0[i]-mnew), p1 = __expf(s1[i]-mnew);
      float ps = p0+p1;
      #pragma unroll
      for (int off=16; off; off>>=1) ps += __shfl_xor(ps, off, 32);
      l[i] = l[i]*alpha + ps;
      m[i] = mnew;
      O[i][0]*=alpha; O[i][1]*=alpha; O[i][2]*=alpha; O[i][3]*=alpha;
      *(float2*)&Ps[ty*4+i][k0] = make_float2(p0,p1);
    }
    __syncthreads();
    for (int k=0;k<64;k+=2){
      float2 p[4];
      #pragma unroll
      for (int i=0;i<4;i++) p[i] = *(const float2*)&Ps[ty*4+i][k];
      float va0=Ks[k][c0], va1=Ks[k][c0+1], va2=Ks[k][c0+2], va3=Ks[k][c0+3];
      float vb0=Ks[k+1][c0], vb1=Ks[k+1][c0+1], vb2=Ks[k+1][c0+2], vb3=Ks[k+1][c0+3];
      #pragma unroll
      for (int i=0;i<4;i++){
        O[i][0] += p[i].x*va0 + p[i].y*vb0;
        O[i][1] += p[i].x*va1 + p[i].y*vb1;
        O[i][2] += p[i].x*va2 + p[i].y*vb2;
        O[i][3] += p[i].x*va3 + p[i].y*vb3;
      }
    }
  }
  #pragma unroll
  for (int i=0;i<4;i++){
    int r = qbase + ty*4 + i;
    float inv = 1.0f / l[i];
    float4 xv = *(const float4*)&x[(size_t)r*D + c0];
    float4 o;
    o.x = xv.x - O[i][0]*inv; o.y = xv.y - O[i][1]*inv;
    o.z = xv.z - O[i][2]*inv; o.w = xv.w - O[i][3]*inv;
    *(float4*)&attin[(size_t)r*D + c0] = o;
  }
}

// ---------------- per-feature mean/var over nodes ----------------
__global__ __launch_bounds__(256) void k_colstats(const float* __restrict__ outb, int N,
                                                  float* __restrict__ mu, float* __restrict__ rstd){
  __shared__ float red[256];
  __shared__ float mval_s;
  int f = blockIdx.x, t = threadIdx.x;
  float s = 0.f;
  for (int r=t; r<N; r+=256) s += outb[(size_t)r*D + f];
  red[t] = s; __syncthreads();
  for (int off=128; off; off>>=1){ if (t<off) red[t]+=red[t+off]; __syncthreads(); }
  if (t==0) mval_s = red[0]/(float)N;
  __syncthreads();
  float mval = mval_s;
  float v = 0.f;
  for (int r=t; r<N; r+=256){ float d0 = outb[(size_t)r*D+f]-mval; v += d0*d0; }
  red[t]=v; __syncthreads();
  for (int off=128; off; off>>=1){ if (t<off) red[t]+=red[t+off]; __syncthreads(); }
  if (t==0){ mu[f]=mval; rstd[f]=rsqrtf(red[0]/(float)N + 1e-5f); }
}

__global__ void k_norm(const float* __restrict__ outb, const float* __restrict__ mu,
                       const float* __restrict__ rstd, const float* __restrict__ gamma,
                       const float* __restrict__ beta, float* __restrict__ x, int N){
  __shared__ float smu[128], srs[128], sg[128], sb[128];
  if (threadIdx.x < 128){ int f=threadIdx.x; smu[f]=mu[f]; srs[f]=rstd[f]; sg[f]=gamma[f]; sb[f]=beta[f]; }
  __syncthreads();
  int i = blockIdx.x*blockDim.x + threadIdx.x;
  int tot = N*32;
  for (; i<tot; i+=gridDim.x*blockDim.x){
    int f0 = (i&31)*4;
    float4 v = *(const float4*)&outb[(size_t)i*4];
    float4 r;
    r.x = (v.x - smu[f0+0])*srs[f0+0]*sg[f0+0]+sb[f0+0];
    r.y = (v.y - smu[f0+1])*srs[f0+1]*sg[f0+1]+sb[f0+1];
    r.z = (v.z - smu[f0+2])*srs[f0+2]*sg[f0+2]+sb[f0+2];
    r.w = (v.w - smu[f0+3])*srs[f0+3]*sg[f0+3]+sb[f0+3];
    *(float4*)&x[(size_t)i*4] = r;
  }
}

// ---------------- gated readout ----------------
__global__ __launch_bounds__(256) void k_gatepool(
    const float* __restrict__ states, const float* __restrict__ glog,
    int N1, int N, float* __restrict__ gsums)
{
  __shared__ float part[256];
  part[threadIdx.x] = 0.f;
  __syncthreads();
  int wid = threadIdx.x >> 6, lane = threadIdx.x & 63;
  for (int v = blockIdx.x*4 + wid; v < N; v += gridDim.x*4){
    float a0 = glog[(size_t)v*D + lane], a1 = glog[(size_t)v*D + lane + 64];
    float mx = fmaxf(a0,a1);
    #pragma unroll
    for (int off=32; off; off>>=1) mx = fmaxf(mx, __shfl_xor(mx, off, 64));
    float e0 = __expf(a0-mx), e1 = __expf(a1-mx);
    float ss = e0+e1;
    #pragma unroll
    for (int off=32; off; off>>=1) ss += __shfl_xor(ss, off, 64);
    float inv = 1.f/ss;
    int g = (v < N1) ? 0 : 1;
    atomicAdd(&part[g*128 + lane], states[(size_t)v*D+lane]*e0*inv);
    atomicAdd(&part[g*128 + lane + 64], states[(size_t)v*D+lane+64]*e1*inv);
  }
  __syncthreads();
  atomicAdd(&gsums[threadIdx.x], part[threadIdx.x]);
}

__global__ __launch_bounds__(256) void k_emb(
    const float* __restrict__ gsums, const float* __restrict__ Wf,
    const float* __restrict__ bf_, int N1, int N2, float* __restrict__ outp)
{
  __shared__ float mean[256];
  int t = threadIdx.x;
  mean[t] = gsums[t] / ((t < 128) ? (float)N1 : (float)N2);
  __syncthreads();
  int g = t >> 7, dc = t & 127;
  float acc = bf_[dc];
  for (int k=0;k<D;k++) acc += mean[g*128 + k] * Wf[k*D + dc];
  outp[t] = acc;
}

extern "C" void kernel_launch(void* const* d_in, const int* in_sizes, int n_in,
                              void* d_out, int out_size, void* d_ws, size_t ws_size,
                              hipStream_t stream) {
  const float* feats1 = (const float*)d_in[0];
  const int*   ei1    = (const int*)d_in[1];
  const float* feats2 = (const float*)d_in[2];
  const int*   ei2    = (const int*)d_in[3];
  const float* Wn = (const float*)d_in[6];
  const float* bn = (const float*)d_in[7];
  const float* Wm = (const float*)d_in[8];
  const float* bm = (const float*)d_in[9];
  const float* Wp = (const float*)d_in[10];
  const float* bp = (const float*)d_in[11];
  const float* gamma = (const float*)d_in[12];
  const float* beta  = (const float*)d_in[13];
  const float* Wa = (const float*)d_in[14];
  const float* ba = (const float*)d_in[15];
  const float* Wg = (const float*)d_in[16];
  const float* bg = (const float*)d_in[17];
  const float* Wf = (const float*)d_in[18];
  const float* bff = (const float*)d_in[19];

  int N1 = in_sizes[0]/D, E1 = in_sizes[1]/2;
  int N2 = in_sizes[2]/D, E2 = in_sizes[3]/2;
  int N = N1+N2;

  char* w = (char*)d_ws;
  size_t matB = (size_t)N*D*sizeof(float);
  float* x     = (float*)w; w += matB;   // persistent node features
  float* attin = (float*)w; w += matB;   // x - cross (flash output)
  float* h     = (float*)w; w += matB;   // also reused for `states`
  float* S     = (float*)w; w += matB;   // neighbor sums; reused for `outb`
  float* aggr  = (float*)w; w += matB;   // also reused for `glog`
  int* cnt    = (int*)w; w += (size_t)N*sizeof(int);
  int* ptr    = (int*)w; w += (size_t)N*sizeof(int);
  int* cursor = (int*)w; w += (size_t)N*sizeof(int);
  float* degf = (float*)w; w += (size_t)N*sizeof(float);
  int* srclist= (int*)w; w += (size_t)(E1+E2)*sizeof(int);
  float* mu   = (float*)w; w += 512;
  float* rstd = (float*)w; w += 512;
  float* gsums= (float*)w; w += 1024;

  hipMemsetAsync(cnt, 0, (size_t)N*sizeof(int), stream);
  k_copy<<<768,256,0,stream>>>(feats1, x, N1*D/4);
  k_copy<<<768,256,0,stream>>>(feats2, x + (size_t)N1*D, N2*D/4);
  k_count<<<1024,256,0,stream>>>(ei1, ei2, E1, E2, N1, cnt);
  k_scan<<<1,256,0,stream>>>(cnt, ptr, cursor, degf, N);
  k_fill<<<1024,256,0,stream>>>(ei1, ei2, E1, E2, N1, cursor, srclist);

  for (int l=0;l<3;l++){
    const float* Wn_l = Wn + (size_t)l*D*D;
    const float* bn_l = bn + (size_t)l*D;
    const float* Wm_l = Wm + (size_t)l*2*D*D;
    const float* bm_l = bm + (size_t)l*D;
    const float* Wp_l = Wp + (size_t)l*2*D*D;
    const float* bp_l = bp + (size_t)l*D;

    // cross-attention first (reads x only), then message path, then proj
    k_flash_attin<<<N/32,256,0,stream>>>(x, N1, N2, attin);
    k_matmul<<<N/64,256,0,stream>>>(x, Wn_l, nullptr, nullptr, bn_l, nullptr, nullptr, h, N);
    k_gather<<<N/2,256,0,stream>>>(h, ptr, cnt, srclist, S, N);
    // aggr = deg.*(h@Wm_top) + S@Wm_bot + deg.*bm
    k_matmul<<<N/64,256,0,stream>>>(h, Wm_l, S, Wm_l + D*D, bm_l, degf, degf, aggr, N);
    // outb (into S buffer) = aggr@Wp_top + attin@Wp_bot + bp
    k_matmul<<<N/64,256,0,stream>>>(aggr, Wp_l, attin, Wp_l + D*D, bp_l, nullptr, nullptr, S, N);
    k_colstats<<<128,256,0,stream>>>(S, N, mu, rstd);
    k_norm<<<768,256,0,stream>>>(S, mu, rstd, gamma + (size_t)l*D, beta + (size_t)l*D, x, N);
  }

  k_matmul<<<N/64,256,0,stream>>>(x, Wa, nullptr, nullptr, ba, nullptr, nullptr, h, N);     // states
  k_matmul<<<N/64,256,0,stream>>>(x, Wg, nullptr, nullptr, bg, nullptr, nullptr, aggr, N);  // gate logits
  hipMemsetAsync(gsums, 0, 256*sizeof(float), stream);
  k_gatepool<<<64,256,0,stream>>>(h, aggr, N1, N, gsums);
  k_emb<<<1,256,0,stream>>>(gsums, Wf, bff, N1, N2, (float*)d_out);
}

// Round 3
// 1236.854 us; speedup vs baseline: 5.7881x; 5.7881x over previous
//
#include <hip/hip_runtime.h>
#include <hip/hip_bf16.h>

#define D 128
typedef unsigned short u16;
typedef unsigned int u32;
typedef __attribute__((ext_vector_type(8))) short short8;
typedef __attribute__((ext_vector_type(16))) float f32x16;
typedef __attribute__((ext_vector_type(4))) u32 u32x4;

__device__ __forceinline__ u16 f2bf(float f){
  u32 u = __builtin_bit_cast(u32, f);
  u32 r = (u + 0x7FFFu + ((u >> 16) & 1u)) >> 16;
  return (u16)r;
}

// ---------------- f32 copy ----------------
__global__ void k_copy(const float* __restrict__ src, float* __restrict__ dst, int n4){
  int i = blockIdx.x*blockDim.x + threadIdx.x;
  for (; i < n4; i += gridDim.x*blockDim.x){
    ((float4*)dst)[i] = ((const float4*)src)[i];
  }
}

// ---------------- CSR build ----------------
__global__ void k_count(const int* __restrict__ ei1, const int* __restrict__ ei2,
                        int E1, int E2, int N1, int* __restrict__ cnt){
  int i = blockIdx.x*blockDim.x + threadIdx.x;
  int Et = E1 + E2;
  for (; i < Et; i += gridDim.x*blockDim.x){
    int dst = (i < E1) ? ei1[E1 + i] : (ei2[E2 + (i - E1)] + N1);
    atomicAdd(&cnt[dst], 1);
  }
}

__global__ void k_scan(const int* __restrict__ cnt, int* __restrict__ ptr,
                       int* __restrict__ cursor, float* __restrict__ degf, int N){
  __shared__ int part[256];
  int t = threadIdx.x;
  int per = (N + 255) >> 8;
  int lo = t*per, hi = min(N, lo+per);
  int s = 0;
  for (int j=lo;j<hi;j++) s += cnt[j];
  part[t] = s; __syncthreads();
  if (t==0){ int acc=0; for (int j=0;j<256;j++){ int v=part[j]; part[j]=acc; acc+=v; } }
  __syncthreads();
  int acc = part[t];
  for (int j=lo;j<hi;j++){ ptr[j]=acc; cursor[j]=acc; degf[j]=(float)cnt[j]; acc += cnt[j]; }
}

__global__ void k_fill(const int* __restrict__ ei1, const int* __restrict__ ei2,
                       int E1, int E2, int N1, int* __restrict__ cursor, int* __restrict__ srclist){
  int i = blockIdx.x*blockDim.x + threadIdx.x;
  int Et = E1 + E2;
  for (; i < Et; i += gridDim.x*blockDim.x){
    int src, dst;
    if (i < E1){ src = ei1[i]; dst = ei1[E1+i]; }
    else { int j = i - E1; src = ei2[j] + N1; dst = ei2[E2+j] + N1; }
    int p = atomicAdd(&cursor[dst], 1);
    srclist[p] = src;
  }
}

// S[v] = sum over in-edges of h[src]
__global__ __launch_bounds__(256) void k_gather(const float* __restrict__ h, const int* __restrict__ ptr,
                          const int* __restrict__ cnt, const int* __restrict__ srclist,
                          float* __restrict__ S, int N){
  int f = threadIdx.x & 127, sub = threadIdx.x >> 7;
  int v = blockIdx.x*2 + sub;
  if (v >= N) return;
  int b = ptr[v], n = cnt[v];
  float acc = 0.f;
  for (int j=0;j<n;j++){ acc += h[(size_t)srclist[b+j]*D + f]; }
  S[(size_t)v*D + f] = acc;
}

// ---------------- generic N x 128 GEMM:  Y = (sA.A)@W1 [+ B@W2] + bscale*bias ----------------
__global__ __launch_bounds__(256) void k_matmul(
    const float* __restrict__ A, const float* __restrict__ W1,
    const float* __restrict__ B, const float* __restrict__ W2,
    const float* __restrict__ bias,
    const float* __restrict__ rowScaleA, const float* __restrict__ biasScale,
    float* __restrict__ Y, int N)
{
  __shared__ float As[64][D];
  __shared__ float Bs[64][D];
  int t = threadIdx.x;
  int tx = t & 31, ty = t >> 5;
  int c0 = tx * 4;
  int rb = blockIdx.x * 64;
  if (rb >= N) return;
  for (int idx = t; idx < 64*32; idx += 256){
    int r = idx >> 5, cc = (idx & 31) * 4;
    float4 av = *(const float4*)&A[(size_t)(rb+r)*D + cc];
    if (rowScaleA){ float sc = rowScaleA[rb+r]; av.x*=sc; av.y*=sc; av.z*=sc; av.w*=sc; }
    *(float4*)&As[r][cc] = av;
    if (B) *(float4*)&Bs[r][cc] = *(const float4*)&B[(size_t)(rb+r)*D + cc];
  }
  __syncthreads();
  float acc[8][4];
  #pragma unroll
  for (int i=0;i<8;i++){ acc[i][0]=0.f;acc[i][1]=0.f;acc[i][2]=0.f;acc[i][3]=0.f; }
  for (int k=0;k<D;k++){
    float4 wv = *(const float4*)&W1[k*D + c0];
    #pragma unroll
    for (int i=0;i<8;i++){
      float a = As[ty*8+i][k];
      acc[i][0] += a*wv.x; acc[i][1] += a*wv.y; acc[i][2] += a*wv.z; acc[i][3] += a*wv.w;
    }
  }
  if (B){
    for (int k=0;k<D;k++){
      float4 wv = *(const float4*)&W2[k*D + c0];
      #pragma unroll
      for (int i=0;i<8;i++){
        float b = Bs[ty*8+i][k];
        acc[i][0] += b*wv.x; acc[i][1] += b*wv.y; acc[i][2] += b*wv.z; acc[i][3] += b*wv.w;
      }
    }
  }
  float b0=0.f,b1=0.f,b2=0.f,b3=0.f;
  if (bias){ float4 bv = *(const float4*)&bias[c0]; b0=bv.x; b1=bv.y; b2=bv.z; b3=bv.w; }
  #pragma unroll
  for (int i=0;i<8;i++){
    int r = rb + ty*8 + i;
    float bs = biasScale ? biasScale[r] : 1.0f;
    float4 o; o.x = acc[i][0] + b0*bs; o.y = acc[i][1] + b1*bs; o.z = acc[i][2] + b2*bs; o.w = acc[i][3] + b3*bs;
    *(float4*)&Y[(size_t)r*D + c0] = o;
  }
}

// ---------------- bf16 convert + transpose: xb [N][128], xbT [128][N] ----------------
__global__ __launch_bounds__(256) void k_cvt(const float* __restrict__ x, u16* __restrict__ xb,
                                             u16* __restrict__ xbT, int N){
  __shared__ u16 tile[128][136];
  int nb = blockIdx.x * 128;
  int t = threadIdx.x;
  int n = t >> 1;
  int ch = t & 1;
  #pragma unroll
  for (int i=0;i<16;i++){
    int dd = ch*64 + i*4;
    float4 v = *(const float4*)&x[(size_t)(nb+n)*D + dd];
    u16 b0 = f2bf(v.x), b1 = f2bf(v.y), b2 = f2bf(v.z), b3 = f2bf(v.w);
    ushort4 uv; uv.x=b0; uv.y=b1; uv.z=b2; uv.w=b3;
    *(ushort4*)&xb[(size_t)(nb+n)*D + dd] = uv;
    tile[dd+0][n]=b0; tile[dd+1][n]=b1; tile[dd+2][n]=b2; tile[dd+3][n]=b3;
  }
  __syncthreads();
  int d = t & 127, hf = t >> 7;
  #pragma unroll
  for (int i=0;i<8;i++){
    short8 v = *(const short8*)&tile[d][hf*64 + i*8];
    *(short8*)&xbT[(size_t)d*N + nb + hf*64 + i*8] = v;
  }
}

// ---------------- MFMA flash cross-attention ----------------
// block = 32 q rows; 4 waves each take a quarter of KV; combine at end. attin = x - softmax(QK^T)V
__global__ __launch_bounds__(256, 2) void k_flash_mfma(
    const float* __restrict__ x, const u16* __restrict__ xb, const u16* __restrict__ xbT,
    int N1, int N2, int Ntot, float* __restrict__ attin)
{
  __shared__ __align__(16) u16 smem[4][8192];   // per wave: K [32][128] swz (8KB) + Vt [128][32] swz (8KB)
  __shared__ float mlbuf[4][32][2];

  const int t = threadIdx.x;
  const int w = t >> 6;
  const int lane = t & 63;
  const int l31 = lane & 31;
  const int hi = lane >> 5;

  const int qbase = blockIdx.x * 32;
  const bool isY = qbase >= N1;
  const int kv0 = isY ? 0 : N1;
  const int kvlen = isY ? N1 : N2;
  const int perw = kvlen >> 2;
  const int kstart = kv0 + w * perw;
  const int ntiles = perw >> 5;

  u16* Klds = &smem[w][0];
  u16* Vlds = &smem[w][4096];

  // Q fragments (B operand of S^T): lane: q = l31, k(d) = 16c + 8*hi + e
  short8 qf[8];
  #pragma unroll
  for (int c = 0; c < 8; ++c)
    qf[c] = *(const short8*)(xb + (size_t)(qbase + l31)*D + c*16 + hi*8);

  f32x16 O[4];
  #pragma unroll
  for (int mt=0; mt<4; ++mt)
    #pragma unroll
    for (int i=0;i<16;i++) O[mt][i] = 0.f;
  float m_run = -3.0e38f, l_run = 0.0f;

  for (int tt = 0; tt < ntiles; ++tt){
    const int kb = kstart + tt*32;
    // ---- stage K (row-major [key][128], byte ^= (key&7)<<4)
    #pragma unroll
    for (int cc = 0; cc < 8; ++cc){
      int chunk = cc*2 + hi;   // 16B granule index 0..15
      short8 v = *(const short8*)(xb + (size_t)(kb + l31)*D + chunk*8);
      *(short8*)((char*)Klds + l31*256 + ((chunk ^ (l31 & 7))*16)) = v;
    }
    // ---- stage Vt ([d][32 keys], granule j -> j ^ (d&3)) from pre-transposed xbT
    #pragma unroll
    for (int cc = 0; cc < 8; ++cc){
      int dd = (lane >> 2) + cc*16;
      int g = lane & 3;
      short8 v = *(const short8*)(xbT + (size_t)dd*Ntot + kb + g*8);
      *(short8*)((char*)Vlds + dd*64 + (((g ^ dd) & 3)*16)) = v;
    }

    // ---- S^T = K @ Q^T  (two independent mfma chains)
    f32x16 sa, sb;
    #pragma unroll
    for (int i=0;i<16;i++){ sa[i]=0.f; sb[i]=0.f; }
    #pragma unroll
    for (int c = 0; c < 8; c += 2){
      int gr0 = 2*c + hi;
      short8 ka = *(const short8*)((const char*)Klds + l31*256 + ((gr0 ^ (l31&7))*16));
      sa = __builtin_amdgcn_mfma_f32_32x32x16_bf16(ka, qf[c], sa, 0,0,0);
      int gr1 = 2*(c+1) + hi;
      short8 kbf = *(const short8*)((const char*)Klds + l31*256 + ((gr1 ^ (l31&7))*16));
      sb = __builtin_amdgcn_mfma_f32_32x32x16_bf16(kbf, qf[c+1], sb, 0,0,0);
    }
    f32x16 s;
    #pragma unroll
    for (int i=0;i<16;i++) s[i] = sa[i] + sb[i];

    // ---- online softmax (per q = lane&31; keys live in 16 regs + other half)
    float tm = s[0];
    #pragma unroll
    for (int i=1;i<16;i++) tm = fmaxf(tm, s[i]);
    tm = fmaxf(tm, __shfl_xor(tm, 32, 64));
    float mnew = fmaxf(m_run, tm);
    float alpha = __expf(m_run - mnew);
    float rs = 0.f;
    #pragma unroll
    for (int i=0;i<16;i++){ float p = __expf(s[i]-mnew); s[i]=p; rs += p; }
    rs += __shfl_xor(rs, 32, 64);
    l_run = l_run*alpha + rs;
    m_run = mnew;
    #pragma unroll
    for (int i=0;i<16;i++){ O[0][i]*=alpha; O[1][i]*=alpha; O[2][i]*=alpha; O[3][i]*=alpha; }

    // ---- pack P to bf16 pairs
    u32 pk[8];
    #pragma unroll
    for (int i=0;i<8;i++){
      u32 r;
      asm("v_cvt_pk_bf16_f32 %0, %1, %2" : "=v"(r) : "v"(s[2*i]), "v"(s[2*i+1]));
      pk[i] = r;
    }

    // ---- PV: O^T += V^T @ P^T
    #pragma unroll
    for (int ks=0; ks<2; ++ks){
      u32 send0 = hi ? pk[(2*ks)*2+0] : pk[(2*ks+1)*2+0];
      u32 send1 = hi ? pk[(2*ks)*2+1] : pk[(2*ks+1)*2+1];
      u32 xv0 = (u32)__shfl_xor((int)send0, 32, 64);
      u32 xv1 = (u32)__shfl_xor((int)send1, 32, 64);
      u32 own0 = hi ? pk[(2*ks+1)*2+0] : pk[(2*ks)*2+0];
      u32 own1 = hi ? pk[(2*ks+1)*2+1] : pk[(2*ks)*2+1];
      u32x4 bv;
      bv.x = hi ? xv0 : own0;
      bv.y = hi ? xv1 : own1;
      bv.z = hi ? own0 : xv0;
      bv.w = hi ? own1 : xv1;
      short8 pf = __builtin_bit_cast(short8, bv);
      #pragma unroll
      for (int mt=0; mt<4; ++mt){
        int dd = mt*32 + l31;
        int j = 2*ks + hi;
        short8 vf = *(const short8*)((const char*)Vlds + dd*64 + (((j ^ dd) & 3)*16));
        O[mt] = __builtin_amdgcn_mfma_f32_32x32x16_bf16(vf, pf, O[mt], 0,0,0);
      }
    }
  }

  // ---- write partials to LDS and combine
  float* Obuf = (float*)&smem[w][0];   // [128 d][32 q]
  #pragma unroll
  for (int mt=0; mt<4; ++mt){
    #pragma unroll
    for (int r=0;r<16;r++){
      int dd = mt*32 + (r&3) + 8*(r>>2) + 4*hi;
      Obuf[dd*32 + l31] = O[mt][r];
    }
  }
  if (lane < 32){ mlbuf[w][l31][0] = m_run; mlbuf[w][l31][1] = l_run; }
  __syncthreads();

  {
    int q = t & 31;
    int d0 = (t >> 5) * 16;
    float m0 = mlbuf[0][q][0], m1 = mlbuf[1][q][0], m2 = mlbuf[2][q][0], m3 = mlbuf[3][q][0];
    float M = fmaxf(fmaxf(m0,m1), fmaxf(m2,m3));
    float w0 = __expf(m0-M), w1 = __expf(m1-M), w2 = __expf(m2-M), w3 = __expf(m3-M);
    float L = w0*mlbuf[0][q][1] + w1*mlbuf[1][q][1] + w2*mlbuf[2][q][1] + w3*mlbuf[3][q][1];
    float invL = 1.0f / L;
    const float* P0 = (const float*)&smem[0][0];
    const float* P1 = (const float*)&smem[1][0];
    const float* P2 = (const float*)&smem[2][0];
    const float* P3 = (const float*)&smem[3][0];
    #pragma unroll
    for (int i=0;i<16;i+=4){
      float4 xr = *(const float4*)&x[(size_t)(qbase+q)*D + d0 + i];
      float o[4];
      #pragma unroll
      for (int j=0;j<4;j++){
        int idx = (d0+i+j)*32 + q;
        o[j] = (w0*P0[idx] + w1*P1[idx] + w2*P2[idx] + w3*P3[idx]) * invL;
      }
      float4 ov; ov.x = xr.x - o[0]; ov.y = xr.y - o[1]; ov.z = xr.z - o[2]; ov.w = xr.w - o[3];
      *(float4*)&attin[(size_t)(qbase+q)*D + d0 + i] = ov;
    }
  }
}

// ---------------- per-feature mean/var over nodes ----------------
__global__ __launch_bounds__(256) void k_colstats(const float* __restrict__ outb, int N,
                                                  float* __restrict__ mu, float* __restrict__ rstd){
  __shared__ float red[256];
  __shared__ float mval_s;
  int f = blockIdx.x, t = threadIdx.x;
  float s = 0.f;
  for (int r=t; r<N; r+=256) s += outb[(size_t)r*D + f];
  red[t] = s; __syncthreads();
  for (int off=128; off; off>>=1){ if (t<off) red[t]+=red[t+off]; __syncthreads(); }
  if (t==0) mval_s = red[0]/(float)N;
  __syncthreads();
  float mval = mval_s;
  float v = 0.f;
  for (int r=t; r<N; r+=256){ float d0 = outb[(size_t)r*D+f]-mval; v += d0*d0; }
  red[t]=v; __syncthreads();
  for (int off=128; off; off>>=1){ if (t<off) red[t]+=red[t+off]; __syncthreads(); }
  if (t==0){ mu[f]=mval; rstd[f]=rsqrtf(red[0]/(float)N + 1e-5f); }
}

__global__ void k_norm(const float* __restrict__ outb, const float* __restrict__ mu,
                       const float* __restrict__ rstd, const float* __restrict__ gamma,
                       const float* __restrict__ beta, float* __restrict__ x, int N){
  __shared__ float smu[128], srs[128], sg[128], sb[128];
  if (threadIdx.x < 128){ int f=threadIdx.x; smu[f]=mu[f]; srs[f]=rstd[f]; sg[f]=gamma[f]; sb[f]=beta[f]; }
  __syncthreads();
  int i = blockIdx.x*blockDim.x + threadIdx.x;
  int tot = N*32;
  for (; i<tot; i+=gridDim.x*blockDim.x){
    int f0 = (i&31)*4;
    float4 v = *(const float4*)&outb[(size_t)i*4];
    float4 r;
    r.x = (v.x - smu[f0+0])*srs[f0+0]*sg[f0+0]+sb[f0+0];
    r.y = (v.y - smu[f0+1])*srs[f0+1]*sg[f0+1]+sb[f0+1];
    r.z = (v.z - smu[f0+2])*srs[f0+2]*sg[f0+2]+sb[f0+2];
    r.w = (v.w - smu[f0+3])*srs[f0+3]*sg[f0+3]+sb[f0+3];
    *(float4*)&x[(size_t)i*4] = r;
  }
}

// ---------------- gated readout ----------------
__global__ __launch_bounds__(256) void k_gatepool(
    const float* __restrict__ states, const float* __restrict__ glog,
    int N1, int N, float* __restrict__ gsums)
{
  __shared__ float part[256];
  part[threadIdx.x] = 0.f;
  __syncthreads();
  int wid = threadIdx.x >> 6, lane = threadIdx.x & 63;
  for (int v = blockIdx.x*4 + wid; v < N; v += gridDim.x*4){
    float a0 = glog[(size_t)v*D + lane], a1 = glog[(size_t)v*D + lane + 64];
    float mx = fmaxf(a0,a1);
    #pragma unroll
    for (int off=32; off; off>>=1) mx = fmaxf(mx, __shfl_xor(mx, off, 64));
    float e0 = __expf(a0-mx), e1 = __expf(a1-mx);
    float ss = e0+e1;
    #pragma unroll
    for (int off=32; off; off>>=1) ss += __shfl_xor(ss, off, 64);
    float inv = 1.f/ss;
    int g = (v < N1) ? 0 : 1;
    atomicAdd(&part[g*128 + lane], states[(size_t)v*D+lane]*e0*inv);
    atomicAdd(&part[g*128 + lane + 64], states[(size_t)v*D+lane+64]*e1*inv);
  }
  __syncthreads();
  atomicAdd(&gsums[threadIdx.x], part[threadIdx.x]);
}

__global__ __launch_bounds__(256) void k_emb(
    const float* __restrict__ gsums, const float* __restrict__ Wf,
    const float* __restrict__ bf_, int N1, int N2, float* __restrict__ outp)
{
  __shared__ float mean[256];
  int t = threadIdx.x;
  mean[t] = gsums[t] / ((t < 128) ? (float)N1 : (float)N2);
  __syncthreads();
  int g = t >> 7, dc = t & 127;
  float acc = bf_[dc];
  for (int k=0;k<D;k++) acc += mean[g*128 + k] * Wf[k*D + dc];
  outp[t] = acc;
}

extern "C" void kernel_launch(void* const* d_in, const int* in_sizes, int n_in,
                              void* d_out, int out_size, void* d_ws, size_t ws_size,
                              hipStream_t stream) {
  const float* feats1 = (const float*)d_in[0];
  const int*   ei1    = (const int*)d_in[1];
  const float* feats2 = (const float*)d_in[2];
  const int*   ei2    = (const int*)d_in[3];
  const float* Wn = (const float*)d_in[6];
  const float* bn = (const float*)d_in[7];
  const float* Wm = (const float*)d_in[8];
  const float* bm = (const float*)d_in[9];
  const float* Wp = (const float*)d_in[10];
  const float* bp = (const float*)d_in[11];
  const float* gamma = (const float*)d_in[12];
  const float* beta  = (const float*)d_in[13];
  const float* Wa = (const float*)d_in[14];
  const float* ba = (const float*)d_in[15];
  const float* Wg = (const float*)d_in[16];
  const float* bg = (const float*)d_in[17];
  const float* Wf = (const float*)d_in[18];
  const float* bff = (const float*)d_in[19];

  int N1 = in_sizes[0]/D, E1 = in_sizes[1]/2;
  int N2 = in_sizes[2]/D, E2 = in_sizes[3]/2;
  int N = N1+N2;

  char* w = (char*)d_ws;
  size_t matB = (size_t)N*D*sizeof(float);
  float* x     = (float*)w; w += matB;   // persistent node features
  float* attin = (float*)w; w += matB;   // x - cross (flash output)
  float* h     = (float*)w; w += matB;   // also: xb (bf16), states
  float* S     = (float*)w; w += matB;   // neighbor sums; also outb
  float* aggr  = (float*)w; w += matB;   // also: xbT (bf16), glog
  int* cnt    = (int*)w; w += (size_t)N*sizeof(int);
  int* ptr    = (int*)w; w += (size_t)N*sizeof(int);
  int* cursor = (int*)w; w += (size_t)N*sizeof(int);
  float* degf = (float*)w; w += (size_t)N*sizeof(float);
  int* srclist= (int*)w; w += (size_t)(E1+E2)*sizeof(int);
  float* mu   = (float*)w; w += 512;
  float* rstd = (float*)w; w += 512;
  float* gsums= (float*)w; w += 1024;

  u16* xb  = (u16*)h;
  u16* xbT = (u16*)aggr;

  hipMemsetAsync(cnt, 0, (size_t)N*sizeof(int), stream);
  k_copy<<<768,256,0,stream>>>(feats1, x, N1*D/4);
  k_copy<<<768,256,0,stream>>>(feats2, x + (size_t)N1*D, N2*D/4);
  k_count<<<1024,256,0,stream>>>(ei1, ei2, E1, E2, N1, cnt);
  k_scan<<<1,256,0,stream>>>(cnt, ptr, cursor, degf, N);
  k_fill<<<1024,256,0,stream>>>(ei1, ei2, E1, E2, N1, cursor, srclist);

  for (int l=0;l<3;l++){
    const float* Wn_l = Wn + (size_t)l*D*D;
    const float* bn_l = bn + (size_t)l*D;
    const float* Wm_l = Wm + (size_t)l*2*D*D;
    const float* bm_l = bm + (size_t)l*D;
    const float* Wp_l = Wp + (size_t)l*2*D*D;
    const float* bp_l = bp + (size_t)l*D;

    // cross-attention (MFMA flash) first: needs bf16 copies of current x
    k_cvt<<<N/128,256,0,stream>>>(x, xb, xbT, N);
    k_flash_mfma<<<N/32,256,0,stream>>>(x, xb, xbT, N1, N2, N, attin);
    // message path (overwrites xb/xbT buffers only after flash is done; stream-ordered)
    k_matmul<<<N/64,256,0,stream>>>(x, Wn_l, nullptr, nullptr, bn_l, nullptr, nullptr, h, N);
    k_gather<<<N/2,256,0,stream>>>(h, ptr, cnt, srclist, S, N);
    k_matmul<<<N/64,256,0,stream>>>(h, Wm_l, S, Wm_l + D*D, bm_l, degf, degf, aggr, N);
    k_matmul<<<N/64,256,0,stream>>>(aggr, Wp_l, attin, Wp_l + D*D, bp_l, nullptr, nullptr, S, N);
    k_colstats<<<128,256,0,stream>>>(S, N, mu, rstd);
    k_norm<<<768,256,0,stream>>>(S, mu, rstd, gamma + (size_t)l*D, beta + (size_t)l*D, x, N);
  }

  k_matmul<<<N/64,256,0,stream>>>(x, Wa, nullptr, nullptr, ba, nullptr, nullptr, h, N);     // states
  k_matmul<<<N/64,256,0,stream>>>(x, Wg, nullptr, nullptr, bg, nullptr, nullptr, aggr, N);  // gate logits
  hipMemsetAsync(gsums, 0, 256*sizeof(float), stream);
  k_gatepool<<<64,256,0,stream>>>(h, aggr, N1, N, gsums);
  k_emb<<<1,256,0,stream>>>(gsums, Wf, bff, N1, N2, (float*)d_out);
}

// Round 4
// 902.803 us; speedup vs baseline: 7.9298x; 1.3700x over previous
//
#include <hip/hip_runtime.h>
#include <hip/hip_bf16.h>

#define D 128
#define KVS 4
typedef unsigned short u16;
typedef unsigned int u32;
typedef __attribute__((ext_vector_type(8))) short short8;
typedef __attribute__((ext_vector_type(16))) float f32x16;
typedef __attribute__((ext_vector_type(4))) u32 u32x4;

__device__ __forceinline__ u16 f2bf(float f){
  u32 u = __builtin_bit_cast(u32, f);
  u32 r = (u + 0x7FFFu + ((u >> 16) & 1u)) >> 16;
  return (u16)r;
}

// ---------------- f32 copy ----------------
__global__ void k_copy(const float* __restrict__ src, float* __restrict__ dst, int n4){
  int i = blockIdx.x*blockDim.x + threadIdx.x;
  for (; i < n4; i += gridDim.x*blockDim.x){
    ((float4*)dst)[i] = ((const float4*)src)[i];
  }
}

// ---------------- CSR build ----------------
__global__ void k_count(const int* __restrict__ ei1, const int* __restrict__ ei2,
                        int E1, int E2, int N1, int* __restrict__ cnt){
  int i = blockIdx.x*blockDim.x + threadIdx.x;
  int Et = E1 + E2;
  for (; i < Et; i += gridDim.x*blockDim.x){
    int dst = (i < E1) ? ei1[E1 + i] : (ei2[E2 + (i - E1)] + N1);
    atomicAdd(&cnt[dst], 1);
  }
}

__global__ void k_scan(const int* __restrict__ cnt, int* __restrict__ ptr,
                       int* __restrict__ cursor, float* __restrict__ degf, int N){
  __shared__ int part[256];
  int t = threadIdx.x;
  int per = (N + 255) >> 8;
  int lo = t*per, hi = min(N, lo+per);
  int s = 0;
  for (int j=lo;j<hi;j++) s += cnt[j];
  part[t] = s; __syncthreads();
  if (t==0){ int acc=0; for (int j=0;j<256;j++){ int v=part[j]; part[j]=acc; acc+=v; } }
  __syncthreads();
  int acc = part[t];
  for (int j=lo;j<hi;j++){ ptr[j]=acc; cursor[j]=acc; degf[j]=(float)cnt[j]; acc += cnt[j]; }
}

__global__ void k_fill(const int* __restrict__ ei1, const int* __restrict__ ei2,
                       int E1, int E2, int N1, int* __restrict__ cursor, int* __restrict__ srclist){
  int i = blockIdx.x*blockDim.x + threadIdx.x;
  int Et = E1 + E2;
  for (; i < Et; i += gridDim.x*blockDim.x){
    int src, dst;
    if (i < E1){ src = ei1[i]; dst = ei1[E1+i]; }
    else { int j = i - E1; src = ei2[j] + N1; dst = ei2[E2+j] + N1; }
    int p = atomicAdd(&cursor[dst], 1);
    srclist[p] = src;
  }
}

// S[v] = sum over in-edges of h[src], 4-way unrolled
__global__ __launch_bounds__(256) void k_gather(const float* __restrict__ h, const int* __restrict__ ptr,
                          const int* __restrict__ cnt, const int* __restrict__ srclist,
                          float* __restrict__ S, int N){
  int f = threadIdx.x & 127, sub = threadIdx.x >> 7;
  int v = blockIdx.x*2 + sub;
  if (v >= N) return;
  int b = ptr[v], n = cnt[v];
  float a0=0.f, a1=0.f, a2=0.f, a3=0.f;
  int j=0;
  for (; j+3<n; j+=4){
    int s0=srclist[b+j], s1=srclist[b+j+1], s2=srclist[b+j+2], s3=srclist[b+j+3];
    a0 += h[(size_t)s0*D + f];
    a1 += h[(size_t)s1*D + f];
    a2 += h[(size_t)s2*D + f];
    a3 += h[(size_t)s3*D + f];
  }
  for (; j<n; j++) a0 += h[(size_t)srclist[b+j]*D + f];
  S[(size_t)v*D + f] = (a0+a1)+(a2+a3);
}

// ---------------- generic N x 128 GEMM:  Y = (sA.A)@W1 [+ B@W2] + bscale*bias ----------------
__global__ __launch_bounds__(256) void k_matmul(
    const float* __restrict__ A, const float* __restrict__ W1,
    const float* __restrict__ B, const float* __restrict__ W2,
    const float* __restrict__ bias,
    const float* __restrict__ rowScaleA, const float* __restrict__ biasScale,
    float* __restrict__ Y, int N)
{
  __shared__ float As[64][D];
  __shared__ float Bs[64][D];
  int t = threadIdx.x;
  int tx = t & 31, ty = t >> 5;
  int c0 = tx * 4;
  int rb = blockIdx.x * 64;
  if (rb >= N) return;
  for (int idx = t; idx < 64*32; idx += 256){
    int r = idx >> 5, cc = (idx & 31) * 4;
    float4 av = *(const float4*)&A[(size_t)(rb+r)*D + cc];
    if (rowScaleA){ float sc = rowScaleA[rb+r]; av.x*=sc; av.y*=sc; av.z*=sc; av.w*=sc; }
    *(float4*)&As[r][cc] = av;
    if (B) *(float4*)&Bs[r][cc] = *(const float4*)&B[(size_t)(rb+r)*D + cc];
  }
  __syncthreads();
  float acc[8][4];
  #pragma unroll
  for (int i=0;i<8;i++){ acc[i][0]=0.f;acc[i][1]=0.f;acc[i][2]=0.f;acc[i][3]=0.f; }
  for (int k=0;k<D;k++){
    float4 wv = *(const float4*)&W1[k*D + c0];
    #pragma unroll
    for (int i=0;i<8;i++){
      float a = As[ty*8+i][k];
      acc[i][0] += a*wv.x; acc[i][1] += a*wv.y; acc[i][2] += a*wv.z; acc[i][3] += a*wv.w;
    }
  }
  if (B){
    for (int k=0;k<D;k++){
      float4 wv = *(const float4*)&W2[k*D + c0];
      #pragma unroll
      for (int i=0;i<8;i++){
        float b = Bs[ty*8+i][k];
        acc[i][0] += b*wv.x; acc[i][1] += b*wv.y; acc[i][2] += b*wv.z; acc[i][3] += b*wv.w;
      }
    }
  }
  float b0=0.f,b1=0.f,b2=0.f,b3=0.f;
  if (bias){ float4 bv = *(const float4*)&bias[c0]; b0=bv.x; b1=bv.y; b2=bv.z; b3=bv.w; }
  #pragma unroll
  for (int i=0;i<8;i++){
    int r = rb + ty*8 + i;
    float bs = biasScale ? biasScale[r] : 1.0f;
    float4 o; o.x = acc[i][0] + b0*bs; o.y = acc[i][1] + b1*bs; o.z = acc[i][2] + b2*bs; o.w = acc[i][3] + b3*bs;
    *(float4*)&Y[(size_t)r*D + c0] = o;
  }
}

// ---------------- bf16 convert + transpose: xb [N][128], xbT [128][N] ----------------
__global__ __launch_bounds__(256) void k_cvt(const float* __restrict__ x, u16* __restrict__ xb,
                                             u16* __restrict__ xbT, int N){
  __shared__ u16 tile[128][136];
  int nb = blockIdx.x * 128;
  int t = threadIdx.x;
  int n = t >> 1;
  int ch = t & 1;
  #pragma unroll
  for (int i=0;i<16;i++){
    int dd = ch*64 + i*4;
    float4 v = *(const float4*)&x[(size_t)(nb+n)*D + dd];
    u16 b0 = f2bf(v.x), b1 = f2bf(v.y), b2 = f2bf(v.z), b3 = f2bf(v.w);
    ushort4 uv; uv.x=b0; uv.y=b1; uv.z=b2; uv.w=b3;
    *(ushort4*)&xb[(size_t)(nb+n)*D + dd] = uv;
    tile[dd+0][n]=b0; tile[dd+1][n]=b1; tile[dd+2][n]=b2; tile[dd+3][n]=b3;
  }
  __syncthreads();
  int d = t & 127, hf = t >> 7;
  #pragma unroll
  for (int i=0;i<8;i++){
    short8 v = *(const short8*)&tile[d][hf*64 + i*8];
    *(short8*)&xbT[(size_t)d*N + nb + hf*64 + i*8] = v;
  }
}

// ---------------- MFMA flash cross-attention, shared-KV staging + KV split ----------------
// block = 4 waves, each one 32-q strip (128 q total); KV quarter per block.
// Writes partial O^T [128 d][32 q] + (m,l) per strip x split.
__global__ __launch_bounds__(256, 2) void k_flash_mfma(
    const u16* __restrict__ xb, const u16* __restrict__ xbT,
    int N1, int N2, int Ntot,
    float* __restrict__ Opart, float* __restrict__ MLpart)
{
  __shared__ __align__(16) u16 Kbuf[2][4096];   // [32 key][128 d], granule^=(row&7)
  __shared__ __align__(16) u16 Vbuf[2][4096];   // [128 d][32 key], granule^=(d&3)

  const int t = threadIdx.x;
  const int w = t >> 6;
  const int lane = t & 63;
  const int l31 = lane & 31;
  const int hi = lane >> 5;

  const int qb = blockIdx.x / KVS;
  const int sp = blockIdx.x % KVS;
  const int qbase = qb * 128;
  const int qs = qbase + w*32;
  const bool isY = qbase >= N1;
  const int kv0 = isY ? 0 : N1;
  const int kvlen = isY ? N1 : N2;
  const int Lk = kvlen / KVS;
  const int kstart = kv0 + sp*Lk;
  const int ntiles = Lk >> 5;

  // Q fragments: lane q = l31, d-chunk = c*16 + hi*8
  short8 qf[8];
  #pragma unroll
  for (int c = 0; c < 8; ++c)
    qf[c] = *(const short8*)(xb + (size_t)(qs + l31)*D + c*16 + hi*8);

  // staging slot assignment (per thread, 2 consecutive 16B slots each for K and Vt)
  const int kr = t >> 3;             // K row 0..31  (slots i=2t,2t+1: row=i>>4)
  const int kg = (t & 7) * 2;        // K granule 0..14 even
  const int vd = t >> 1;             // Vt d 0..127  (slots i=2t,2t+1: dd=i>>2)
  const int vj = (t & 1) * 2;        // Vt granule 0/2
  const int kw0 = kr*256 + ((kg     ^ (kr & 7))*16);
  const int kw1 = kr*256 + (((kg+1) ^ (kr & 7))*16);
  const int vw0 = vd*64  + (((vj     ^ vd) & 3)*16);
  const int vw1 = vd*64  + ((((vj+1) ^ vd) & 3)*16);

  f32x16 O[4];
  #pragma unroll
  for (int mt=0; mt<4; ++mt)
    #pragma unroll
    for (int i=0;i<16;i++) O[mt][i] = 0.f;
  float m_run = -3.0e38f, l_run = 0.0f;

  // prologue: stage tile 0 into buf0
  {
    int kb = kstart;
    short8 a0 = *(const short8*)(xb  + (size_t)(kb+kr)*D + kg*8);
    short8 a1 = *(const short8*)(xb  + (size_t)(kb+kr)*D + (kg+1)*8);
    short8 v0 = *(const short8*)(xbT + (size_t)vd*Ntot + kb + vj*8);
    short8 v1 = *(const short8*)(xbT + (size_t)vd*Ntot + kb + (vj+1)*8);
    *(short8*)((char*)&Kbuf[0][0] + kw0) = a0;
    *(short8*)((char*)&Kbuf[0][0] + kw1) = a1;
    *(short8*)((char*)&Vbuf[0][0] + vw0) = v0;
    *(short8*)((char*)&Vbuf[0][0] + vw1) = v1;
  }
  __syncthreads();

  for (int tt = 0; tt < ntiles; ++tt){
    const int cur = tt & 1;
    const int nxt = cur ^ 1;
    // issue next-tile loads early (latency hides under compute)
    short8 a0, a1, v0, v1;
    const bool more = (tt+1 < ntiles);
    if (more){
      int kb = kstart + (tt+1)*32;
      a0 = *(const short8*)(xb  + (size_t)(kb+kr)*D + kg*8);
      a1 = *(const short8*)(xb  + (size_t)(kb+kr)*D + (kg+1)*8);
      v0 = *(const short8*)(xbT + (size_t)vd*Ntot + kb + vj*8);
      v1 = *(const short8*)(xbT + (size_t)vd*Ntot + kb + (vj+1)*8);
    }

    const char* Klds = (const char*)&Kbuf[cur][0];
    const char* Vlds = (const char*)&Vbuf[cur][0];

    // ---- S^T = K @ Q^T
    f32x16 sa, sb;
    #pragma unroll
    for (int i=0;i<16;i++){ sa[i]=0.f; sb[i]=0.f; }
    #pragma unroll
    for (int c = 0; c < 8; c += 2){
      int gr0 = 2*c + hi;
      short8 ka = *(const short8*)(Klds + l31*256 + ((gr0 ^ (l31&7))*16));
      sa = __builtin_amdgcn_mfma_f32_32x32x16_bf16(ka, qf[c], sa, 0,0,0);
      int gr1 = 2*(c+1) + hi;
      short8 kbf = *(const short8*)(Klds + l31*256 + ((gr1 ^ (l31&7))*16));
      sb = __builtin_amdgcn_mfma_f32_32x32x16_bf16(kbf, qf[c+1], sb, 0,0,0);
    }
    f32x16 s;
    #pragma unroll
    for (int i=0;i<16;i++) s[i] = sa[i] + sb[i];

    // ---- online softmax (per q = lane&31)
    float tm = s[0];
    #pragma unroll
    for (int i=1;i<16;i++) tm = fmaxf(tm, s[i]);
    tm = fmaxf(tm, __shfl_xor(tm, 32, 64));
    float mnew = fmaxf(m_run, tm);
    float alpha = __expf(m_run - mnew);
    float rs = 0.f;
    #pragma unroll
    for (int i=0;i<16;i++){ float p = __expf(s[i]-mnew); s[i]=p; rs += p; }
    rs += __shfl_xor(rs, 32, 64);
    l_run = l_run*alpha + rs;
    m_run = mnew;
    #pragma unroll
    for (int i=0;i<16;i++){ O[0][i]*=alpha; O[1][i]*=alpha; O[2][i]*=alpha; O[3][i]*=alpha; }

    // ---- pack P to bf16 pairs
    u32 pk[8];
    #pragma unroll
    for (int i=0;i<8;i++){
      u32 r;
      asm("v_cvt_pk_bf16_f32 %0, %1, %2" : "=v"(r) : "v"(s[2*i]), "v"(s[2*i+1]));
      pk[i] = r;
    }

    // ---- PV: O^T += V^T @ P^T
    #pragma unroll
    for (int ks=0; ks<2; ++ks){
      u32 send0 = hi ? pk[(2*ks)*2+0] : pk[(2*ks+1)*2+0];
      u32 send1 = hi ? pk[(2*ks)*2+1] : pk[(2*ks+1)*2+1];
      u32 xv0 = (u32)__shfl_xor((int)send0, 32, 64);
      u32 xv1 = (u32)__shfl_xor((int)send1, 32, 64);
      u32 own0 = hi ? pk[(2*ks+1)*2+0] : pk[(2*ks)*2+0];
      u32 own1 = hi ? pk[(2*ks+1)*2+1] : pk[(2*ks)*2+1];
      u32x4 bv;
      bv.x = hi ? xv0 : own0;
      bv.y = hi ? xv1 : own1;
      bv.z = hi ? own0 : xv0;
      bv.w = hi ? own1 : xv1;
      short8 pf = __builtin_bit_cast(short8, bv);
      #pragma unroll
      for (int mt=0; mt<4; ++mt){
        int dd = mt*32 + l31;
        int j = 2*ks + hi;
        short8 vf = *(const short8*)(Vlds + dd*64 + (((j ^ dd) & 3)*16));
        O[mt] = __builtin_amdgcn_mfma_f32_32x32x16_bf16(vf, pf, O[mt], 0,0,0);
      }
    }

    // ---- write next tile into other buffer (vmcnt wait lands here), then barrier
    if (more){
      *(short8*)((char*)&Kbuf[nxt][0] + kw0) = a0;
      *(short8*)((char*)&Kbuf[nxt][0] + kw1) = a1;
      *(short8*)((char*)&Vbuf[nxt][0] + vw0) = v0;
      *(short8*)((char*)&Vbuf[nxt][0] + vw1) = v1;
    }
    __syncthreads();
  }

  // ---- write partials (O^T as [128 d][32 q]) + (m,l)
  const int strip = qs >> 5;              // global q-strip id
  float* Od = Opart + ((size_t)strip*KVS + sp)*4096;
  #pragma unroll
  for (int mt=0; mt<4; ++mt){
    #pragma unroll
    for (int r=0;r<16;r++){
      int dd = mt*32 + (r&3) + 8*(r>>2) + 4*hi;
      Od[dd*32 + l31] = O[mt][r];
    }
  }
  if (lane < 32){
    float* mlp = MLpart + ((size_t)strip*KVS + sp)*64;
    mlp[l31*2+0] = m_run;
    mlp[l31*2+1] = l_run;
  }
}

// ---------------- flash partial combine: attin = x - (sum_s w_s O_s)/L ----------------
__global__ __launch_bounds__(256) void k_fcomb(
    const float* __restrict__ Opart, const float* __restrict__ MLpart,
    const float* __restrict__ x, float* __restrict__ attin)
{
  __shared__ float cw[KVS][32];
  __shared__ float Tld[128][33];
  const int strip = blockIdx.x;
  const int t = threadIdx.x;
  if (t < 32){
    int q = t;
    const float* mlp = MLpart + (size_t)strip*KVS*64;
    float m0=mlp[0*64+q*2], l0=mlp[0*64+q*2+1];
    float m1=mlp[1*64+q*2], l1=mlp[1*64+q*2+1];
    float m2=mlp[2*64+q*2], l2=mlp[2*64+q*2+1];
    float m3=mlp[3*64+q*2], l3=mlp[3*64+q*2+1];
    float M = fmaxf(fmaxf(m0,m1), fmaxf(m2,m3));
    float w0=__expf(m0-M), w1=__expf(m1-M), w2=__expf(m2-M), w3=__expf(m3-M);
    float Ls = w0*l0 + w1*l1 + w2*l2 + w3*l3;
    float inv = 1.0f / Ls;
    cw[0][q]=w0*inv; cw[1][q]=w1*inv; cw[2][q]=w2*inv; cw[3][q]=w3*inv;
  }
  __syncthreads();
  {
    const int d = t >> 1, q0 = (t & 1) * 16;
    const float* Ob = Opart + (size_t)strip*KVS*4096;
    float acc[16];
    #pragma unroll
    for (int j=0;j<16;j++) acc[j]=0.f;
    #pragma unroll
    for (int s2=0; s2<KVS; ++s2){
      const float* row = Ob + s2*4096 + d*32 + q0;
      #pragma unroll
      for (int j4=0;j4<16;j4+=4){
        float4 v = *(const float4*)&row[j4];
        acc[j4+0] += cw[s2][q0+j4+0]*v.x;
        acc[j4+1] += cw[s2][q0+j4+1]*v.y;
        acc[j4+2] += cw[s2][q0+j4+2]*v.z;
        acc[j4+3] += cw[s2][q0+j4+3]*v.w;
      }
    }
    #pragma unroll
    for (int j=0;j<16;j++) Tld[d][q0+j] = acc[j];
  }
  __syncthreads();
  {
    const int q = t >> 3, c0 = (t & 7) * 16;
    const size_t row = (size_t)(strip*32 + q)*D;
    #pragma unroll
    for (int i=0;i<16;i+=4){
      float4 xr = *(const float4*)&x[row + c0 + i];
      float4 ov;
      ov.x = xr.x - Tld[c0+i+0][q];
      ov.y = xr.y - Tld[c0+i+1][q];
      ov.z = xr.z - Tld[c0+i+2][q];
      ov.w = xr.w - Tld[c0+i+3][q];
      *(float4*)&attin[row + c0 + i] = ov;
    }
  }
}

// ---------------- per-feature mean/var over nodes ----------------
__global__ __launch_bounds__(256) void k_colstats(const float* __restrict__ outb, int N,
                                                  float* __restrict__ mu, float* __restrict__ rstd){
  __shared__ float red[256];
  __shared__ float mval_s;
  int f = blockIdx.x, t = threadIdx.x;
  float s = 0.f;
  for (int r=t; r<N; r+=256) s += outb[(size_t)r*D + f];
  red[t] = s; __syncthreads();
  for (int off=128; off; off>>=1){ if (t<off) red[t]+=red[t+off]; __syncthreads(); }
  if (t==0) mval_s = red[0]/(float)N;
  __syncthreads();
  float mval = mval_s;
  float v = 0.f;
  for (int r=t; r<N; r+=256){ float d0 = outb[(size_t)r*D+f]-mval; v += d0*d0; }
  red[t]=v; __syncthreads();
  for (int off=128; off; off>>=1){ if (t<off) red[t]+=red[t+off]; __syncthreads(); }
  if (t==0){ mu[f]=mval; rstd[f]=rsqrtf(red[0]/(float)N + 1e-5f); }
}

__global__ void k_norm(const float* __restrict__ outb, const float* __restrict__ mu,
                       const float* __restrict__ rstd, const float* __restrict__ gamma,
                       const float* __restrict__ beta, float* __restrict__ x, int N){
  __shared__ float smu[128], srs[128], sg[128], sb[128];
  if (threadIdx.x < 128){ int f=threadIdx.x; smu[f]=mu[f]; srs[f]=rstd[f]; sg[f]=gamma[f]; sb[f]=beta[f]; }
  __syncthreads();
  int i = blockIdx.x*blockDim.x + threadIdx.x;
  int tot = N*32;
  for (; i<tot; i+=gridDim.x*blockDim.x){
    int f0 = (i&31)*4;
    float4 v = *(const float4*)&outb[(size_t)i*4];
    float4 r;
    r.x = (v.x - smu[f0+0])*srs[f0+0]*sg[f0+0]+sb[f0+0];
    r.y = (v.y - smu[f0+1])*srs[f0+1]*sg[f0+1]+sb[f0+1];
    r.z = (v.z - smu[f0+2])*srs[f0+2]*sg[f0+2]+sb[f0+2];
    r.w = (v.w - smu[f0+3])*srs[f0+3]*sg[f0+3]+sb[f0+3];
    *(float4*)&x[(size_t)i*4] = r;
  }
}

// ---------------- gated readout ----------------
__global__ __launch_bounds__(256) void k_gatepool(
    const float* __restrict__ states, const float* __restrict__ glog,
    int N1, int N, float* __restrict__ gsums)
{
  __shared__ float part[256];
  part[threadIdx.x] = 0.f;
  __syncthreads();
  int wid = threadIdx.x >> 6, lane = threadIdx.x & 63;
  for (int v = blockIdx.x*4 + wid; v < N; v += gridDim.x*4){
    float a0 = glog[(size_t)v*D + lane], a1 = glog[(size_t)v*D + lane + 64];
    float mx = fmaxf(a0,a1);
    #pragma unroll
    for (int off=32; off; off>>=1) mx = fmaxf(mx, __shfl_xor(mx, off, 64));
    float e0 = __expf(a0-mx), e1 = __expf(a1-mx);
    float ss = e0+e1;
    #pragma unroll
    for (int off=32; off; off>>=1) ss += __shfl_xor(ss, off, 64);
    float inv = 1.f/ss;
    int g = (v < N1) ? 0 : 1;
    atomicAdd(&part[g*128 + lane], states[(size_t)v*D+lane]*e0*inv);
    atomicAdd(&part[g*128 + lane + 64], states[(size_t)v*D+lane+64]*e1*inv);
  }
  __syncthreads();
  atomicAdd(&gsums[threadIdx.x], part[threadIdx.x]);
}

__global__ __launch_bounds__(256) void k_emb(
    const float* __restrict__ gsums, const float* __restrict__ Wf,
    const float* __restrict__ bf_, int N1, int N2, float* __restrict__ outp)
{
  __shared__ float mean[256];
  int t = threadIdx.x;
  mean[t] = gsums[t] / ((t < 128) ? (float)N1 : (float)N2);
  __syncthreads();
  int g = t >> 7, dc = t & 127;
  float acc = bf_[dc];
  for (int k=0;k<D;k++) acc += mean[g*128 + k] * Wf[k*D + dc];
  outp[t] = acc;
}

extern "C" void kernel_launch(void* const* d_in, const int* in_sizes, int n_in,
                              void* d_out, int out_size, void* d_ws, size_t ws_size,
                              hipStream_t stream) {
  const float* feats1 = (const float*)d_in[0];
  const int*   ei1    = (const int*)d_in[1];
  const float* feats2 = (const float*)d_in[2];
  const int*   ei2    = (const int*)d_in[3];
  const float* Wn = (const float*)d_in[6];
  const float* bn = (const float*)d_in[7];
  const float* Wm = (const float*)d_in[8];
  const float* bm = (const float*)d_in[9];
  const float* Wp = (const float*)d_in[10];
  const float* bp = (const float*)d_in[11];
  const float* gamma = (const float*)d_in[12];
  const float* beta  = (const float*)d_in[13];
  const float* Wa = (const float*)d_in[14];
  const float* ba = (const float*)d_in[15];
  const float* Wg = (const float*)d_in[16];
  const float* bg = (const float*)d_in[17];
  const float* Wf = (const float*)d_in[18];
  const float* bff = (const float*)d_in[19];

  int N1 = in_sizes[0]/D, E1 = in_sizes[1]/2;
  int N2 = in_sizes[2]/D, E2 = in_sizes[3]/2;
  int N = N1+N2;
  int nstrips = N/32;

  char* w = (char*)d_ws;
  size_t matB = (size_t)N*D*sizeof(float);
  float* x     = (float*)w; w += matB;   // persistent node features
  float* attin = (float*)w; w += matB;   // x - cross
  float* h     = (float*)w; w += matB;   // also: xb (bf16), states
  float* S     = (float*)w; w += matB;   // neighbor sums; also outb
  float* aggr  = (float*)w; w += matB;   // also: xbT (bf16), glog
  int* cnt    = (int*)w; w += (size_t)N*sizeof(int);
  int* ptr    = (int*)w; w += (size_t)N*sizeof(int);
  int* cursor = (int*)w; w += (size_t)N*sizeof(int);
  float* degf = (float*)w; w += (size_t)N*sizeof(float);
  int* srclist= (int*)w; w += (size_t)(E1+E2)*sizeof(int);
  float* mu   = (float*)w; w += 512;
  float* rstd = (float*)w; w += 512;
  float* gsums= (float*)w; w += 1024;
  float* Opart = (float*)w; w += (size_t)nstrips*KVS*4096*sizeof(float);  // ~25 MB
  float* MLpart= (float*)w; w += (size_t)nstrips*KVS*64*sizeof(float);

  u16* xb  = (u16*)h;
  u16* xbT = (u16*)aggr;

  hipMemsetAsync(cnt, 0, (size_t)N*sizeof(int), stream);
  k_copy<<<768,256,0,stream>>>(feats1, x, N1*D/4);
  k_copy<<<768,256,0,stream>>>(feats2, x + (size_t)N1*D, N2*D/4);
  k_count<<<1024,256,0,stream>>>(ei1, ei2, E1, E2, N1, cnt);
  k_scan<<<1,256,0,stream>>>(cnt, ptr, cursor, degf, N);
  k_fill<<<1024,256,0,stream>>>(ei1, ei2, E1, E2, N1, cursor, srclist);

  for (int l=0;l<3;l++){
    const float* Wn_l = Wn + (size_t)l*D*D;
    const float* bn_l = bn + (size_t)l*D;
    const float* Wm_l = Wm + (size_t)l*2*D*D;
    const float* bm_l = bm + (size_t)l*D;
    const float* Wp_l = Wp + (size_t)l*2*D*D;
    const float* bp_l = bp + (size_t)l*D;

    // cross-attention (MFMA flash, shared staging, KV-split partials)
    k_cvt<<<N/128,256,0,stream>>>(x, xb, xbT, N);
    k_flash_mfma<<<(N/128)*KVS,256,0,stream>>>(xb, xbT, N1, N2, N, Opart, MLpart);
    k_fcomb<<<nstrips,256,0,stream>>>(Opart, MLpart, x, attin);
    // message path
    k_matmul<<<N/64,256,0,stream>>>(x, Wn_l, nullptr, nullptr, bn_l, nullptr, nullptr, h, N);
    k_gather<<<N/2,256,0,stream>>>(h, ptr, cnt, srclist, S, N);
    k_matmul<<<N/64,256,0,stream>>>(h, Wm_l, S, Wm_l + D*D, bm_l, degf, degf, aggr, N);
    k_matmul<<<N/64,256,0,stream>>>(aggr, Wp_l, attin, Wp_l + D*D, bp_l, nullptr, nullptr, S, N);
    k_colstats<<<128,256,0,stream>>>(S, N, mu, rstd);
    k_norm<<<768,256,0,stream>>>(S, mu, rstd, gamma + (size_t)l*D, beta + (size_t)l*D, x, N);
  }

  k_matmul<<<N/64,256,0,stream>>>(x, Wa, nullptr, nullptr, ba, nullptr, nullptr, h, N);     // states
  k_matmul<<<N/64,256,0,stream>>>(x, Wg, nullptr, nullptr, bg, nullptr, nullptr, aggr, N);  // gate logits
  hipMemsetAsync(gsums, 0, 256*sizeof(float), stream);
  k_gatepool<<<64,256,0,stream>>>(h, aggr, N1, N, gsums);
  k_emb<<<1,256,0,stream>>>(gsums, Wf, bff, N1, N2, (float*)d_out);
}

// Round 6
// 719.259 us; speedup vs baseline: 9.9533x; 1.2552x over previous
//
#include <hip/hip_runtime.h>
#include <hip/hip_bf16.h>

#define D 128
#define KVS 8
typedef unsigned short u16;
typedef unsigned int u32;
typedef __attribute__((ext_vector_type(8))) short short8;
typedef __attribute__((ext_vector_type(16))) float f32x16;
typedef __attribute__((ext_vector_type(4))) u32 u32x4;

__device__ __forceinline__ u16 f2bf(float f){
  u32 u = __builtin_bit_cast(u32, f);
  u32 r = (u + 0x7FFFu + ((u >> 16) & 1u)) >> 16;
  return (u16)r;
}
__device__ __forceinline__ float bf2f(u16 u){
  union { u32 i; float f; } v; v.i = ((u32)u) << 16; return v.f;
}

// ---------------- f32 copy ----------------
__global__ void k_copy(const float* __restrict__ src, float* __restrict__ dst, int n4){
  int i = blockIdx.x*blockDim.x + threadIdx.x;
  for (; i < n4; i += gridDim.x*blockDim.x){
    ((float4*)dst)[i] = ((const float4*)src)[i];
  }
}

// ---------------- CSR build ----------------
__global__ void k_count(const int* __restrict__ ei1, const int* __restrict__ ei2,
                        int E1, int E2, int N1, int* __restrict__ cnt){
  int i = blockIdx.x*blockDim.x + threadIdx.x;
  int Et = E1 + E2;
  for (; i < Et; i += gridDim.x*blockDim.x){
    int dst = (i < E1) ? ei1[E1 + i] : (ei2[E2 + (i - E1)] + N1);
    atomicAdd(&cnt[dst], 1);
  }
}

__global__ void k_scan(const int* __restrict__ cnt, int* __restrict__ ptr,
                       int* __restrict__ cursor, float* __restrict__ degf, int N){
  __shared__ int part[256];
  int t = threadIdx.x;
  int per = (N + 255) >> 8;
  int lo = t*per, hi = min(N, lo+per);
  int s = 0;
  for (int j=lo;j<hi;j++) s += cnt[j];
  part[t] = s; __syncthreads();
  if (t==0){ int acc=0; for (int j=0;j<256;j++){ int v=part[j]; part[j]=acc; acc+=v; } }
  __syncthreads();
  int acc = part[t];
  for (int j=lo;j<hi;j++){ ptr[j]=acc; cursor[j]=acc; degf[j]=(float)cnt[j]; acc += cnt[j]; }
}

__global__ void k_fill(const int* __restrict__ ei1, const int* __restrict__ ei2,
                       int E1, int E2, int N1, int* __restrict__ cursor, int* __restrict__ srclist){
  int i = blockIdx.x*blockDim.x + threadIdx.x;
  int Et = E1 + E2;
  for (; i < Et; i += gridDim.x*blockDim.x){
    int src, dst;
    if (i < E1){ src = ei1[i]; dst = ei1[E1+i]; }
    else { int j = i - E1; src = ei2[j] + N1; dst = ei2[E2+j] + N1; }
    int p = atomicAdd(&cursor[dst], 1);
    srclist[p] = src;
  }
}

// ---------------- weight convert: f32 [128k][128n] -> bf16 transposed [128n][128k] ----------------
__global__ __launch_bounds__(256) void k_wcvt(const float* __restrict__ Wn, const float* __restrict__ Wm,
                                              const float* __restrict__ Wp, u16* __restrict__ wgt){
  __shared__ u16 tile[128][136];
  int m = blockIdx.x;
  const float* src; u16* dst;
  if (m < 3){ src = Wn + m*16384; dst = wgt + m*16384; }
  else if (m < 9){ int l=(m-3)%3, half=(m-3)/3; src = Wm + l*32768 + half*16384; dst = wgt + (3 + half*3 + l)*16384; }
  else { int l=(m-9)%3, half=(m-9)/3; src = Wp + l*32768 + half*16384; dst = wgt + (9 + half*3 + l)*16384; }
  int t = threadIdx.x;
  int n = t & 127, rh = t >> 7;
  for (int r0=0; r0<128; r0+=2){
    int r = r0 + rh;
    tile[n][r] = f2bf(src[r*128 + n]);
  }
  __syncthreads();
  int row = t >> 1, ch = t & 1;
  #pragma unroll
  for (int i=0;i<4;i++){
    int k0 = ch*64 + i*16;
    short8 a = *(const short8*)&tile[row][k0];
    short8 b = *(const short8*)&tile[row][k0+8];
    *(short8*)&dst[row*128 + k0] = a;
    *(short8*)&dst[row*128 + k0 + 8] = b;
  }
}

// ---------------- bf16 convert + transpose: xb [N][128], xbT [128][N] ----------------
__global__ __launch_bounds__(256) void k_cvt(const float* __restrict__ x, u16* __restrict__ xb,
                                             u16* __restrict__ xbT, int N){
  __shared__ u16 tile[128][136];
  int nb = blockIdx.x * 128;
  int t = threadIdx.x;
  int n = t >> 1;
  int ch = t & 1;
  #pragma unroll
  for (int i=0;i<16;i++){
    int dd = ch*64 + i*4;
    float4 v = *(const float4*)&x[(size_t)(nb+n)*D + dd];
    u16 b0 = f2bf(v.x), b1 = f2bf(v.y), b2 = f2bf(v.z), b3 = f2bf(v.w);
    ushort4 uv; uv.x=b0; uv.y=b1; uv.z=b2; uv.w=b3;
    *(ushort4*)&xb[(size_t)(nb+n)*D + dd] = uv;
    tile[dd+0][n]=b0; tile[dd+1][n]=b1; tile[dd+2][n]=b2; tile[dd+3][n]=b3;
  }
  __syncthreads();
  int d = t & 127, hf = t >> 7;
  #pragma unroll
  for (int i=0;i<8;i++){
    short8 v = *(const short8*)&tile[d][hf*64 + i*8];
    *(short8*)&xbT[(size_t)d*N + nb + hf*64 + i*8] = v;
  }
}

// ---------------- MFMA GEMM: out = rs.*(A@W1 + bias) + B@W2 + addin ----------------
// A,B: [N][128] bf16 row-major; W1T,W2T: [128 out][128 k] bf16 (pre-transposed)
__global__ __launch_bounds__(256) void k_gemm(
    const u16* __restrict__ A, const u16* __restrict__ W1T,
    const u16* __restrict__ B, const u16* __restrict__ W2T,
    const float* __restrict__ bias, const float* __restrict__ rs,
    const float* __restrict__ addin,
    float* __restrict__ of, u16* __restrict__ ob, int N)
{
  __shared__ __align__(16) u16 Wsw[2][16384];
  const int t = threadIdx.x;
  const int w4 = t >> 6;
  const int lane = t & 63;
  const int l31 = lane & 31;
  const int hi = lane >> 5;
  const int rb = blockIdx.x * 32;

  // stage W1T (and W2T) into swizzled LDS [row 128][k 128]
  #pragma unroll
  for (int i=0;i<8;i++){
    int slot = i*256 + t;
    int row = slot >> 4, g = slot & 15;
    short8 v = *(const short8*)(W1T + row*128 + g*8);
    *(short8*)((char*)&Wsw[0][0] + row*256 + ((g ^ (row&7))*16)) = v;
  }
  if (B){
    #pragma unroll
    for (int i=0;i<8;i++){
      int slot = i*256 + t;
      int row = slot >> 4, g = slot & 15;
      short8 v = *(const short8*)(W2T + row*128 + g*8);
      *(short8*)((char*)&Wsw[1][0] + row*256 + ((g ^ (row&7))*16)) = v;
    }
  }
  // A,B fragments direct from global (lane = row within 32-row tile)
  short8 af[8], bfr[8];
  #pragma unroll
  for (int g=0; g<8; g++)
    af[g] = *(const short8*)(A + (size_t)(rb + l31)*D + (2*g + hi)*8);
  if (B){
    #pragma unroll
    for (int g=0; g<8; g++)
      bfr[g] = *(const short8*)(B + (size_t)(rb + l31)*D + (2*g + hi)*8);
  }
  __syncthreads();

  f32x16 acc1, acc2;
  #pragma unroll
  for (int i=0;i<16;i++){ acc1[i]=0.f; acc2[i]=0.f; }
  const int wrow = w4*32 + l31;   // output column
  #pragma unroll
  for (int s=0;s<8;s++){
    int gr = 2*s + hi;
    short8 wf = *(const short8*)((const char*)&Wsw[0][0] + wrow*256 + ((gr ^ (wrow&7))*16));
    acc1 = __builtin_amdgcn_mfma_f32_32x32x16_bf16(af[s], wf, acc1, 0,0,0);
  }
  if (B){
    #pragma unroll
    for (int s=0;s<8;s++){
      int gr = 2*s + hi;
      short8 wf = *(const short8*)((const char*)&Wsw[1][0] + wrow*256 + ((gr ^ (wrow&7))*16));
      acc2 = __builtin_amdgcn_mfma_f32_32x32x16_bf16(bfr[s], wf, acc2, 0,0,0);
    }
  }
  const int col = wrow;
  float bv = bias ? bias[col] : 0.0f;
  #pragma unroll
  for (int r=0;r<16;r++){
    int rr = (r&3) + 8*(r>>2) + 4*hi;
    size_t grow = (size_t)(rb + rr);
    float v = acc1[r] + bv;
    if (rs) v *= rs[grow];
    if (B) v += acc2[r];
    if (addin) v += addin[grow*D + col];
    if (of) of[grow*D + col] = v;
    if (ob) ob[grow*D + col] = f2bf(v);
  }
}

// S[v] = sum over in-edges of hb[src] (bf16 in, f32 out)
__global__ __launch_bounds__(256) void k_gather(const u16* __restrict__ hb, const int* __restrict__ ptr,
                          const int* __restrict__ cnt, const int* __restrict__ srclist,
                          float* __restrict__ Sg, int N){
  int f = threadIdx.x & 127, sub = threadIdx.x >> 7;
  int v = blockIdx.x*2 + sub;
  if (v >= N) return;
  int b = ptr[v], n = cnt[v];
  float a0=0.f, a1=0.f, a2=0.f, a3=0.f;
  int j=0;
  for (; j+3<n; j+=4){
    int s0=srclist[b+j], s1=srclist[b+j+1], s2=srclist[b+j+2], s3=srclist[b+j+3];
    a0 += bf2f(hb[(size_t)s0*D + f]);
    a1 += bf2f(hb[(size_t)s1*D + f]);
    a2 += bf2f(hb[(size_t)s2*D + f]);
    a3 += bf2f(hb[(size_t)s3*D + f]);
  }
  for (; j<n; j++) a0 += bf2f(hb[(size_t)srclist[b+j]*D + f]);
  Sg[(size_t)v*D + f] = (a0+a1)+(a2+a3);
}

// ---------------- MFMA flash cross-attention, shared-KV staging + KV split ----------------
__global__ __launch_bounds__(256, 2) void k_flash_mfma(
    const u16* __restrict__ xb, const u16* __restrict__ xbT,
    int N1, int N2, int Ntot,
    float* __restrict__ Opart, float* __restrict__ MLpart)
{
  __shared__ __align__(16) u16 Kbuf[2][4096];   // [32 key][128 d], granule^=(row&7)
  __shared__ __align__(16) u16 Vbuf[2][4096];   // [128 d][32 key], granule^=(d&3)

  const int t = threadIdx.x;
  const int w = t >> 6;
  const int lane = t & 63;
  const int l31 = lane & 31;
  const int hi = lane >> 5;

  const int qb = blockIdx.x / KVS;
  const int sp = blockIdx.x % KVS;
  const int qbase = qb * 128;
  const int qs = qbase + w*32;
  const bool isY = qbase >= N1;
  const int kv0 = isY ? 0 : N1;
  const int kvlen = isY ? N1 : N2;
  const int Lk = kvlen / KVS;
  const int kstart = kv0 + sp*Lk;
  const int ntiles = Lk >> 5;

  short8 qf[8];
  #pragma unroll
  for (int c = 0; c < 8; ++c)
    qf[c] = *(const short8*)(xb + (size_t)(qs + l31)*D + c*16 + hi*8);

  const int kr = t >> 3;
  const int kg = (t & 7) * 2;
  const int vd = t >> 1;
  const int vj = (t & 1) * 2;
  const int kw0 = kr*256 + ((kg     ^ (kr & 7))*16);
  const int kw1 = kr*256 + (((kg+1) ^ (kr & 7))*16);
  const int vw0 = vd*64  + (((vj     ^ vd) & 3)*16);
  const int vw1 = vd*64  + ((((vj+1) ^ vd) & 3)*16);

  f32x16 O[4];
  #pragma unroll
  for (int mt=0; mt<4; ++mt)
    #pragma unroll
    for (int i=0;i<16;i++) O[mt][i] = 0.f;
  float m_run = -3.0e38f, l_run = 0.0f;

  {
    int kb = kstart;
    short8 a0 = *(const short8*)(xb  + (size_t)(kb+kr)*D + kg*8);
    short8 a1 = *(const short8*)(xb  + (size_t)(kb+kr)*D + (kg+1)*8);
    short8 v0 = *(const short8*)(xbT + (size_t)vd*Ntot + kb + vj*8);
    short8 v1 = *(const short8*)(xbT + (size_t)vd*Ntot + kb + (vj+1)*8);
    *(short8*)((char*)&Kbuf[0][0] + kw0) = a0;
    *(short8*)((char*)&Kbuf[0][0] + kw1) = a1;
    *(short8*)((char*)&Vbuf[0][0] + vw0) = v0;
    *(short8*)((char*)&Vbuf[0][0] + vw1) = v1;
  }
  __syncthreads();

  for (int tt = 0; tt < ntiles; ++tt){
    const int cur = tt & 1;
    const int nxt = cur ^ 1;
    short8 a0, a1, v0, v1;
    const bool more = (tt+1 < ntiles);
    if (more){
      int kb = kstart + (tt+1)*32;
      a0 = *(const short8*)(xb  + (size_t)(kb+kr)*D + kg*8);
      a1 = *(const short8*)(xb  + (size_t)(kb+kr)*D + (kg+1)*8);
      v0 = *(const short8*)(xbT + (size_t)vd*Ntot + kb + vj*8);
      v1 = *(const short8*)(xbT + (size_t)vd*Ntot + kb + (vj+1)*8);
    }

    const char* Klds = (const char*)&Kbuf[cur][0];
    const char* Vlds = (const char*)&Vbuf[cur][0];

    // ---- S^T = K @ Q^T
    f32x16 sa, sb;
    #pragma unroll
    for (int i=0;i<16;i++){ sa[i]=0.f; sb[i]=0.f; }
    #pragma unroll
    for (int c = 0; c < 8; c += 2){
      int gr0 = 2*c + hi;
      short8 ka = *(const short8*)(Klds + l31*256 + ((gr0 ^ (l31&7))*16));
      sa = __builtin_amdgcn_mfma_f32_32x32x16_bf16(ka, qf[c], sa, 0,0,0);
      int gr1 = 2*(c+1) + hi;
      short8 kbf = *(const short8*)(Klds + l31*256 + ((gr1 ^ (l31&7))*16));
      sb = __builtin_amdgcn_mfma_f32_32x32x16_bf16(kbf, qf[c+1], sb, 0,0,0);
    }
    f32x16 s;
    #pragma unroll
    for (int i=0;i<16;i++) s[i] = sa[i] + sb[i];

    // ---- online softmax with defer-max (skip O-rescale when max doesn't grow)
    float tm = s[0];
    #pragma unroll
    for (int i=1;i<16;i++) tm = fmaxf(tm, s[i]);
    tm = fmaxf(tm, __shfl_xor(tm, 32, 64));
    if (__any(tm > m_run + 8.0f)){
      float mnew = fmaxf(m_run, tm);
      float alpha = __expf(m_run - mnew);
      l_run *= alpha;
      m_run = mnew;
      #pragma unroll
      for (int i=0;i<16;i++){ O[0][i]*=alpha; O[1][i]*=alpha; O[2][i]*=alpha; O[3][i]*=alpha; }
    }
    float rsum = 0.f;
    #pragma unroll
    for (int i=0;i<16;i++){ float p = __expf(s[i]-m_run); s[i]=p; rsum += p; }
    rsum += __shfl_xor(rsum, 32, 64);
    l_run += rsum;

    // ---- pack P to bf16 pairs
    u32 pk[8];
    #pragma unroll
    for (int i=0;i<8;i++){
      u32 r;
      asm("v_cvt_pk_bf16_f32 %0, %1, %2" : "=v"(r) : "v"(s[2*i]), "v"(s[2*i+1]));
      pk[i] = r;
    }

    // ---- PV: O^T += V^T @ P^T
    #pragma unroll
    for (int ks=0; ks<2; ++ks){
      u32 send0 = hi ? pk[(2*ks)*2+0] : pk[(2*ks+1)*2+0];
      u32 send1 = hi ? pk[(2*ks)*2+1] : pk[(2*ks+1)*2+1];
      u32 xv0 = (u32)__shfl_xor((int)send0, 32, 64);
      u32 xv1 = (u32)__shfl_xor((int)send1, 32, 64);
      u32 own0 = hi ? pk[(2*ks+1)*2+0] : pk[(2*ks)*2+0];
      u32 own1 = hi ? pk[(2*ks+1)*2+1] : pk[(2*ks)*2+1];
      u32x4 bv;
      bv.x = hi ? xv0 : own0;
      bv.y = hi ? xv1 : own1;
      bv.z = hi ? own0 : xv0;
      bv.w = hi ? own1 : xv1;
      short8 pf = __builtin_bit_cast(short8, bv);
      #pragma unroll
      for (int mt=0; mt<4; ++mt){
        int dd = mt*32 + l31;
        int j = 2*ks + hi;
        short8 vf = *(const short8*)(Vlds + dd*64 + (((j ^ dd) & 3)*16));
        O[mt] = __builtin_amdgcn_mfma_f32_32x32x16_bf16(vf, pf, O[mt], 0,0,0);
      }
    }

    if (more){
      *(short8*)((char*)&Kbuf[nxt][0] + kw0) = a0;
      *(short8*)((char*)&Kbuf[nxt][0] + kw1) = a1;
      *(short8*)((char*)&Vbuf[nxt][0] + vw0) = v0;
      *(short8*)((char*)&Vbuf[nxt][0] + vw1) = v1;
    }
    __syncthreads();
  }

  const int strip = qs >> 5;
  float* Od = Opart + ((size_t)strip*KVS + sp)*4096;
  #pragma unroll
  for (int mt=0; mt<4; ++mt){
    #pragma unroll
    for (int r=0;r<16;r++){
      int dd = mt*32 + (r&3) + 8*(r>>2) + 4*hi;
      Od[dd*32 + l31] = O[mt][r];
    }
  }
  if (lane < 32){
    float* mlp = MLpart + ((size_t)strip*KVS + sp)*64;
    mlp[l31*2+0] = m_run;
    mlp[l31*2+1] = l_run;
  }
}

// ---------------- flash partial combine: attinb = bf16(x - (sum_s w_s O_s)/L) ----------------
__global__ __launch_bounds__(256) void k_fcomb(
    const float* __restrict__ Opart, const float* __restrict__ MLpart,
    const float* __restrict__ x, u16* __restrict__ attinb)
{
  __shared__ float cw[KVS][32];
  __shared__ float Tld[128][33];
  const int strip = blockIdx.x;
  const int t = threadIdx.x;
  if (t < 32){
    int q = t;
    const float* mlp = MLpart + (size_t)strip*KVS*64;
    float mv[KVS], lv[KVS];
    float M = -3.0e38f;
    #pragma unroll
    for (int s2=0;s2<KVS;s2++){ mv[s2]=mlp[s2*64+q*2]; lv[s2]=mlp[s2*64+q*2+1]; M = fmaxf(M, mv[s2]); }
    float L = 0.f;
    #pragma unroll
    for (int s2=0;s2<KVS;s2++){ float wv=__expf(mv[s2]-M); cw[s2][q]=wv; L += wv*lv[s2]; }
    float inv = 1.0f / L;
    #pragma unroll
    for (int s2=0;s2<KVS;s2++) cw[s2][q] *= inv;
  }
  __syncthreads();
  {
    const int d = t >> 1, q0 = (t & 1) * 16;
    const float* Ob = Opart + (size_t)strip*KVS*4096;
    float acc[16];
    #pragma unroll
    for (int j=0;j<16;j++) acc[j]=0.f;
    #pragma unroll
    for (int s2=0; s2<KVS; ++s2){
      const float* row = Ob + s2*4096 + d*32 + q0;
      #pragma unroll
      for (int j4=0;j4<16;j4+=4){
        float4 v = *(const float4*)&row[j4];
        acc[j4+0] += cw[s2][q0+j4+0]*v.x;
        acc[j4+1] += cw[s2][q0+j4+1]*v.y;
        acc[j4+2] += cw[s2][q0+j4+2]*v.z;
        acc[j4+3] += cw[s2][q0+j4+3]*v.w;
      }
    }
    #pragma unroll
    for (int j=0;j<16;j++) Tld[d][q0+j] = acc[j];
  }
  __syncthreads();
  {
    const int q = t >> 3, c0 = (t & 7) * 16;
    const size_t row = (size_t)(strip*32 + q)*D;
    #pragma unroll
    for (int i=0;i<16;i+=4){
      float4 xr = *(const float4*)&x[row + c0 + i];
      ushort4 o;
      o.x = f2bf(xr.x - Tld[c0+i+0][q]);
      o.y = f2bf(xr.y - Tld[c0+i+1][q]);
      o.z = f2bf(xr.z - Tld[c0+i+2][q]);
      o.w = f2bf(xr.w - Tld[c0+i+3][q]);
      *(ushort4*)&attinb[row + c0 + i] = o;
    }
  }
}

// ---------------- coalesced column sums (sum + sumsq) via atomics ----------------
__global__ __launch_bounds__(256) void k_colsum(const float* __restrict__ outb, int N,
                                                float* __restrict__ sums){
  int f = threadIdx.x & 127, sub = threadIdx.x >> 7;
  float s=0.f, q=0.f;
  for (int r = blockIdx.x*2 + sub; r < N; r += gridDim.x*2){
    float v = outb[(size_t)r*D + f]; s += v; q += v*v;
  }
  atomicAdd(&sums[f], s);
  atomicAdd(&sums[128+f], q);
}

// ---------------- norm + f32/bf16/bf16T write fused ----------------
__global__ __launch_bounds__(256) void k_normcvt(const float* __restrict__ outb,
                        const float* __restrict__ sums,
                        const float* __restrict__ gamma, const float* __restrict__ beta,
                        int N, float* __restrict__ x, u16* __restrict__ xb, u16* __restrict__ xbT){
  __shared__ u16 tile[128][136];
  __shared__ float smu[128], srs[128], sg2[128], sb2[128];
  int t = threadIdx.x;
  if (t < 128){
    float mu = sums[t] / (float)N;
    float var = fmaxf(sums[128+t]/(float)N - mu*mu, 0.0f);
    smu[t]=mu; srs[t]=rsqrtf(var + 1e-5f);
    sg2[t]=gamma[t]; sb2[t]=beta[t];
  }
  __syncthreads();
  int nb = blockIdx.x * 128;
  int n = t >> 1, ch = t & 1;
  #pragma unroll
  for (int i=0;i<16;i++){
    int dd = ch*64 + i*4;
    float4 v = *(const float4*)&outb[(size_t)(nb+n)*D + dd];
    float4 y;
    y.x = (v.x - smu[dd+0])*srs[dd+0]*sg2[dd+0] + sb2[dd+0];
    y.y = (v.y - smu[dd+1])*srs[dd+1]*sg2[dd+1] + sb2[dd+1];
    y.z = (v.z - smu[dd+2])*srs[dd+2]*sg2[dd+2] + sb2[dd+2];
    y.w = (v.w - smu[dd+3])*srs[dd+3]*sg2[dd+3] + sb2[dd+3];
    *(float4*)&x[(size_t)(nb+n)*D + dd] = y;
    u16 b0=f2bf(y.x), b1=f2bf(y.y), b2=f2bf(y.z), b3=f2bf(y.w);
    ushort4 uv; uv.x=b0; uv.y=b1; uv.z=b2; uv.w=b3;
    *(ushort4*)&xb[(size_t)(nb+n)*D + dd] = uv;
    tile[dd+0][n]=b0; tile[dd+1][n]=b1; tile[dd+2][n]=b2; tile[dd+3][n]=b3;
  }
  __syncthreads();
  int d = t & 127, hf = t >> 7;
  #pragma unroll
  for (int i=0;i<8;i++){
    short8 v = *(const short8*)&tile[d][hf*64 + i*8];
    *(short8*)&xbT[(size_t)d*N + nb + hf*64 + i*8] = v;
  }
}

// ---------------- f32 matmul (readout only) ----------------
__global__ __launch_bounds__(256) void k_matmul(
    const float* __restrict__ A, const float* __restrict__ W1,
    const float* __restrict__ bias, float* __restrict__ Y, int N)
{
  __shared__ float As[64][D];
  int t = threadIdx.x;
  int tx = t & 31, ty = t >> 5;
  int c0 = tx * 4;
  int rb = blockIdx.x * 64;
  if (rb >= N) return;
  for (int idx = t; idx < 64*32; idx += 256){
    int r = idx >> 5, cc = (idx & 31) * 4;
    *(float4*)&As[r][cc] = *(const float4*)&A[(size_t)(rb+r)*D + cc];
  }
  __syncthreads();
  float acc[8][4];
  #pragma unroll
  for (int i=0;i<8;i++){ acc[i][0]=0.f;acc[i][1]=0.f;acc[i][2]=0.f;acc[i][3]=0.f; }
  for (int k=0;k<D;k++){
    float4 wv = *(const float4*)&W1[k*D + c0];
    #pragma unroll
    for (int i=0;i<8;i++){
      float a = As[ty*8+i][k];
      acc[i][0] += a*wv.x; acc[i][1] += a*wv.y; acc[i][2] += a*wv.z; acc[i][3] += a*wv.w;
    }
  }
  float4 bv = *(const float4*)&bias[c0];
  #pragma unroll
  for (int i=0;i<8;i++){
    int r = rb + ty*8 + i;
    float4 o; o.x = acc[i][0] + bv.x; o.y = acc[i][1] + bv.y; o.z = acc[i][2] + bv.z; o.w = acc[i][3] + bv.w;
    *(float4*)&Y[(size_t)r*D + c0] = o;
  }
}

// ---------------- gated readout ----------------
__global__ __launch_bounds__(256) void k_gatepool(
    const float* __restrict__ states, const float* __restrict__ glog,
    int N1, int N, float* __restrict__ gsums)
{
  __shared__ float part[256];
  part[threadIdx.x] = 0.f;
  __syncthreads();
  int wid = threadIdx.x >> 6, lane = threadIdx.x & 63;
  for (int v = blockIdx.x*4 + wid; v < N; v += gridDim.x*4){
    float a0 = glog[(size_t)v*D + lane], a1 = glog[(size_t)v*D + lane + 64];
    float mx = fmaxf(a0,a1);
    #pragma unroll
    for (int off=32; off; off>>=1) mx = fmaxf(mx, __shfl_xor(mx, off, 64));
    float e0 = __expf(a0-mx), e1 = __expf(a1-mx);
    float ss = e0+e1;
    #pragma unroll
    for (int off=32; off; off>>=1) ss += __shfl_xor(ss, off, 64);
    float inv = 1.f/ss;
    int g = (v < N1) ? 0 : 1;
    atomicAdd(&part[g*128 + lane], states[(size_t)v*D+lane]*e0*inv);
    atomicAdd(&part[g*128 + lane + 64], states[(size_t)v*D+lane+64]*e1*inv);
  }
  __syncthreads();
  atomicAdd(&gsums[threadIdx.x], part[threadIdx.x]);
}

__global__ __launch_bounds__(256) void k_emb(
    const float* __restrict__ gsums, const float* __restrict__ Wf,
    const float* __restrict__ bf_, int N1, int N2, float* __restrict__ outp)
{
  __shared__ float mean[256];
  int t = threadIdx.x;
  mean[t] = gsums[t] / ((t < 128) ? (float)N1 : (float)N2);
  __syncthreads();
  int g = t >> 7, dc = t & 127;
  float acc = bf_[dc];
  for (int k=0;k<D;k++) acc += mean[g*128 + k] * Wf[k*D + dc];
  outp[t] = acc;
}

extern "C" void kernel_launch(void* const* d_in, const int* in_sizes, int n_in,
                              void* d_out, int out_size, void* d_ws, size_t ws_size,
                              hipStream_t stream) {
  const float* feats1 = (const float*)d_in[0];
  const int*   ei1    = (const int*)d_in[1];
  const float* feats2 = (const float*)d_in[2];
  const int*   ei2    = (const int*)d_in[3];
  const float* Wn = (const float*)d_in[6];
  const float* bn = (const float*)d_in[7];
  const float* Wm = (const float*)d_in[8];
  const float* bm = (const float*)d_in[9];
  const float* Wp = (const float*)d_in[10];
  const float* bp = (const float*)d_in[11];
  const float* gamma = (const float*)d_in[12];
  const float* beta  = (const float*)d_in[13];
  const float* Wa = (const float*)d_in[14];
  const float* ba = (const float*)d_in[15];
  const float* Wg = (const float*)d_in[16];
  const float* bg = (const float*)d_in[17];
  const float* Wf = (const float*)d_in[18];
  const float* bff = (const float*)d_in[19];

  int N1 = in_sizes[0]/D, E1 = in_sizes[1]/2;
  int N2 = in_sizes[2]/D, E2 = in_sizes[3]/2;
  int N = N1+N2;
  int nstrips = N/32;

  char* w = (char*)d_ws;
  float* x    = (float*)w; w += (size_t)N*D*4;
  u16* xb     = (u16*)w;   w += (size_t)N*D*2;
  u16* xbT    = (u16*)w;   w += (size_t)N*D*2;
  u16* hb     = (u16*)w;   w += (size_t)N*D*2;
  u16* hm2b   = (u16*)w;   w += (size_t)N*D*2;
  u16* aggrb  = (u16*)w;   w += (size_t)N*D*2;
  u16* attinb = (u16*)w;   w += (size_t)N*D*2;
  int* cnt    = (int*)w;   w += (size_t)N*4;
  int* ptr    = (int*)w;   w += (size_t)N*4;
  int* cursor = (int*)w;   w += (size_t)N*4;
  float* degf = (float*)w; w += (size_t)N*4;
  int* srclist= (int*)w;   w += (size_t)(E1+E2)*4;
  float* sums = (float*)w; w += 1024;
  float* gsums= (float*)w; w += 1024;
  u16* wgt    = (u16*)w;   w += (size_t)15*16384*2;
  float* Opart = (float*)w; w += (size_t)nstrips*KVS*4096*4;
  float* MLpart= (float*)w; w += (size_t)nstrips*KVS*64*4;
  // lifetime-disjoint aliases inside Opart (all used only after k_fcomb of same layer,
  // or after all layers for the readout):
  float* Sg     = Opart;
  float* outb   = Opart + (size_t)N*D;
  float* states = Opart;
  float* glog   = Opart + (size_t)N*D;

  hipMemsetAsync(cnt, 0, (size_t)N*4, stream);
  k_copy<<<768,256,0,stream>>>(feats1, x, N1*D/4);
  k_copy<<<768,256,0,stream>>>(feats2, x + (size_t)N1*D, N2*D/4);
  k_count<<<1024,256,0,stream>>>(ei1, ei2, E1, E2, N1, cnt);
  k_scan<<<1,256,0,stream>>>(cnt, ptr, cursor, degf, N);
  k_fill<<<1024,256,0,stream>>>(ei1, ei2, E1, E2, N1, cursor, srclist);
  k_wcvt<<<15,256,0,stream>>>(Wn, Wm, Wp, wgt);
  k_cvt<<<N/128,256,0,stream>>>(x, xb, xbT, N);

  for (int l=0;l<3;l++){
    const u16* WnT_l  = wgt + (size_t)(0+l)*16384;
    const u16* Wm1T_l = wgt + (size_t)(3+l)*16384;
    const u16* Wm2T_l = wgt + (size_t)(6+l)*16384;
    const u16* Wp1T_l = wgt + (size_t)(9+l)*16384;
    const u16* Wp2T_l = wgt + (size_t)(12+l)*16384;
    const float* bn_l = bn + (size_t)l*D;
    const float* bm_l = bm + (size_t)l*D;
    const float* bp_l = bp + (size_t)l*D;

    k_flash_mfma<<<(N/128)*KVS,256,0,stream>>>(xb, xbT, N1, N2, N, Opart, MLpart);
    k_fcomb<<<nstrips,256,0,stream>>>(Opart, MLpart, x, attinb);
    // h = x@Wn + bn  (bf16 out)
    k_gemm<<<N/32,256,0,stream>>>(xb, WnT_l, nullptr, nullptr, bn_l, nullptr, nullptr, nullptr, hb, N);
    // hm2 = h@Wm_bot (pre-gather message)
    k_gemm<<<N/32,256,0,stream>>>(hb, Wm2T_l, nullptr, nullptr, nullptr, nullptr, nullptr, nullptr, hm2b, N);
    k_gather<<<N/2,256,0,stream>>>(hm2b, ptr, cnt, srclist, Sg, N);
    // aggr = deg.*(h@Wm_top + bm) + Sg
    k_gemm<<<N/32,256,0,stream>>>(hb, Wm1T_l, nullptr, nullptr, bm_l, degf, Sg, nullptr, aggrb, N);
    // outb = aggr@Wp_top + attin@Wp_bot + bp (f32 out)
    k_gemm<<<N/32,256,0,stream>>>(aggrb, Wp1T_l, attinb, Wp2T_l, bp_l, nullptr, nullptr, outb, nullptr, N);
    hipMemsetAsync(sums, 0, 1024, stream);
    k_colsum<<<192,256,0,stream>>>(outb, N, sums);
    k_normcvt<<<N/128,256,0,stream>>>(outb, sums, gamma + (size_t)l*D, beta + (size_t)l*D, N, x, xb, xbT);
  }

  k_matmul<<<N/64,256,0,stream>>>(x, Wa, ba, states, N);
  k_matmul<<<N/64,256,0,stream>>>(x, Wg, bg, glog, N);
  hipMemsetAsync(gsums, 0, 1024, stream);
  k_gatepool<<<64,256,0,stream>>>(states, glog, N1, N, gsums);
  k_emb<<<1,256,0,stream>>>(gsums, Wf, bff, N1, N2, (float*)d_out);
}